// Round 8
// baseline (431.117 us; speedup 1.0000x reference)
//
#include <hip/hip_runtime.h>

typedef unsigned short u16; typedef unsigned int u32; typedef unsigned long long u64;
typedef __attribute__((ext_vector_type(8))) short short8;
typedef __attribute__((ext_vector_type(16))) float f32x16;

#define HW 16384

// fp32 ws region (float index)
#define RED_B  0
#define C1E_B  128
#define C2_B   160
#define OUT_B  416
#define BN_SC  480
#define BN_SH  544
// byte offsets in ws
#define FLAG_OFF   4096
#define RWB_OFF    8192      // bf16 reduce weights, fragment-major [otile(4)][s(16)][lane(64)][8]
#define C1B_OFF    73728     // bf16 [32][128] (kept for fp32 path compat)
#define EMBB_OFF   81920     // bf16 [32][256]
#define OUTB_OFF   98304     // bf16 [64][128]
#define C2PB_OFF   114688    // bf16 [256][288] tap-major (zeros for oc>=200)
#define WEFF_OFF   262144    // bf16 [32][256] = conv1 @ W_red
#define CAT2_OFF   524288    // bf16 [8*16384][128] pixel-major
#define MIX_OFF    34078720  // bf16 [8*16384][32]  pixel-major

__device__ __forceinline__ float bf2f(u16 x){ u32 u=((u32)x)<<16; float f; __builtin_memcpy(&f,&u,4); return f; }
__device__ __forceinline__ u16 f2bf(float f){ u32 u; __builtin_memcpy(&u,&f,4); return (u16)((u + 0x7fffu + ((u>>16)&1u))>>16); }
__device__ __forceinline__ u32 pk2(float a, float b){ return (u32)f2bf(a) | ((u32)f2bf(b)<<16); }
__device__ __forceinline__ float lrelu(float x){ return x>0.f ? x : 0.01f*x; }

template<int M> __device__ __forceinline__ u16 ldb(const void* p, size_t i){
    if (M==1) return ((const u16*)p)[i];
    return f2bf(((const float*)p)[i]);
}
template<int M> __device__ __forceinline__ float ldf(const void* p, size_t i){
    if (M==1) return bf2f(((const u16*)p)[i]);
    return ((const float*)p)[i];
}
// bijective swizzle over pixel-octet AND pixel-within-octet
__device__ __forceinline__ int swz(int p){ return ((p>>1) ^ (p>>3)) & 7; }

// async global->LDS, 16B per lane: LDS dest = uniform base + lane*16; global src per-lane
__device__ __forceinline__ void gl16(const void* g, void* l){
    __builtin_amdgcn_global_load_lds(
        (const __attribute__((address_space(1))) u32*)g,
        (__attribute__((address_space(3))) u32*)l, 16, 0, 0);
}

// ---------------- dtype detector ----------------
__global__ void detect_kernel(const void* __restrict__ emb, u32* __restrict__ flag){
    int tid = threadIdx.x;
    const u16* p = (const u16*)emb;
    int e = (p[tid*2] >> 7) & 0xFF;
    u64 m = __ballot(e >= 100 && e <= 140);
    if (tid == 0) *flag = (__popcll(m) >= 32) ? 1u : 0u;
}

// ---------------- prep ----------------
template<int M>
__device__ __forceinline__ void prep_body(
    const void* rw, const void* rb, const void* c1w, const void* c1b,
    const void* c2w, const void* c2b, const void* ew, const void* eb,
    const void* ow, const void* ob, const void* gam, const void* bet,
    const void* mn, const void* vr, char* ws)
{
    float* wf = (float*)ws;
    int i = blockIdx.x*256 + threadIdx.x;
    if (i < 32768) {
        int o = i>>8, ic = i&255;
        int s = ic>>4, qq = (ic>>3)&1, e = ic&7;
        int dst = (((o>>5)*16 + s)*64 + qq*32 + (o&31))*8 + e;
        ((u16*)(ws+RWB_OFF))[dst] = ldb<M>(rw, i);
    }
    else if (i < 36864)  ((u16*)(ws+C1B_OFF))[i-32768] = ldb<M>(c1w, i-32768);
    else if (i < 45056)  ((u16*)(ws+EMBB_OFF))[i-36864] = ldb<M>(ew, i-36864);
    else if (i < 53248)  ((u16*)(ws+OUTB_OFF))[i-45056] = ldb<M>(ow, i-45056);
    else if (i < 126976) {
        int j = i-53248; int o = j/288, k = j - o*288;
        int tap = k>>5, ic = k&31;
        u16 v = 0;
        if (o < 200) v = ldb<M>(c2w, (size_t)o*288 + ic*9 + tap);
        ((u16*)(ws+C2PB_OFF))[j] = v;
    }
    else if (i < 127584) {
        int j = i-126976;
        if (j < 128) wf[RED_B+j] = ldf<M>(rb, j);
        else if (j < 160) {
            int o = j-128;
            float s = ldf<M>(c1b,o) + ldf<M>(eb,o);
#pragma unroll 8
            for (int ic=0; ic<128; ic++)
                s += ldf<M>(c1w, (size_t)o*128+ic) * ldf<M>(rb, ic);
            wf[C1E_B+o] = s;
        }
        else if (j < 416) { int o = j-160; wf[C2_B+o] = (o<200) ? ldf<M>(c2b,o) : 0.f; }
        else if (j < 480) wf[OUT_B+j-416] = ldf<M>(ob, j-416);
        else if (j < 544) { int c=j-480; wf[BN_SC+c] = ldf<M>(gam,c) * rsqrtf(ldf<M>(vr,c)+1e-5f); }
        else { int c=j-544; wf[BN_SH+c] = ldf<M>(bet,c) - ldf<M>(mn,c)*ldf<M>(gam,c)*rsqrtf(ldf<M>(vr,c)+1e-5f); }
    }
    else if (i < 135776) {
        int j = i - 127584; int oc = j>>8, k2 = j&255;
        float s = 0.f;
#pragma unroll 8
        for (int ic=0; ic<128; ic++)
            s += ldf<M>(c1w, (size_t)oc*128+ic) * ldf<M>(rw, (size_t)ic*256+k2);
        ((u16*)(ws+WEFF_OFF))[oc*256+k2] = f2bf(s);
    }
}

__global__ __launch_bounds__(256) void k_prep(
    const void* rw, const void* rb, const void* c1w, const void* c1b,
    const void* c2w, const void* c2b, const void* ew, const void* eb,
    const void* ow, const void* ob, const void* gam, const void* bet,
    const void* mn, const void* vr, char* ws, const u32* __restrict__ flag)
{
    if (*flag) prep_body<1>(rw,rb,c1w,c1b,c2w,c2b,ew,eb,ow,ob,gam,bet,mn,vr,ws);
    else       prep_body<0>(rw,rb,c1w,c1b,c2w,c2b,ew,eb,ow,ob,gam,bet,mn,vr,ws);
}

// ---------------- bf16 fused reduce+mix: async gload_lds staging ----------------
// grid 2048, 512 thr, 1 block/CU (137 KB LDS).
//  S : ALL inputs -> raw LDS via global_load_lds (zero VGPR, all in flight)  [bar]
//  T : LDS->LDS transpose: thr 0-255 concat->At1, thr 256-511 emb->At2      [bar]
//  P1: 8 waves (pt=wvi>>2, ks=wvi&3): reduce 16 MFMA -> cat2; mix partial
//      4 MFMA (At1, W_eff) + 4 MFMA (At2, embB) — no extra barrier
//  P4: combine 4 K-partials via raw-as-f32-exch                              [bar]
__global__ __launch_bounds__(512) void k_rm(
    const void* __restrict__ hi, const void* __restrict__ lo, const void* __restrict__ emb,
    const u16* __restrict__ rwB, const u16* __restrict__ weffB, const u16* __restrict__ embB,
    const float* __restrict__ wf, u16* __restrict__ cat2, u16* __restrict__ mixt,
    const u32* __restrict__ flag)
{
    if (*flag != 1u) return;
    __shared__ u16 At1[64*264];   // 33792 B  concat, pixel-major swizzled
    __shared__ u16 At2[64*264];   // 33792 B  emb, pixel-major swizzled
    __shared__ u16 raw[34816];    // 69632 B: lo[224][64] | hi[128][32] @14336 | emb[256][64] @18432
                                  // total 137216 B -> 1 block/CU

    const int tid = threadIdx.x, wvi = tid>>6, lane = tid&63;
    const int col = lane&31, q = lane>>5;
    const int gpx = blockIdx.x*64;
    const int b = gpx>>14, p0 = gpx&16383;
    const int h = p0>>7, w0 = p0&127;

    // ---- S: issue all async loads (wave-uniform LDS base, per-lane global src) ----
    {
        // lo: 28 wave-instrs; chunk = i*64+lane -> ch=chunk>>3, p8=chunk&7
        for (int i=wvi; i<28; i+=8){
            int chunk = i*64 + lane;
            int ch = chunk>>3, p8 = chunk&7;
            gl16((const u16*)lo + ((size_t)(b*224+ch))*HW + p0 + p8*8,
                 (char*)raw + i*1024);
        }
        // hi native window: 8 wave-instrs; chunk -> hc=chunk>>2, c4=chunk&3
        {
            int i = wvi;
            int chunk = i*64 + lane;
            int hc = chunk>>2, c4 = chunk&3;
            gl16((const u16*)hi + ((size_t)(b*128+hc))*4096 + (size_t)(h>>1)*64 + (w0>>1) + c4*8,
                 (char*)raw + 28672 + i*1024);
        }
        // emb: 32 wave-instrs
        for (int i=wvi; i<32; i+=8){
            int chunk = i*64 + lane;
            int ch = chunk>>3, p8 = chunk&7;
            gl16((const u16*)emb + ((size_t)(b*256+ch))*HW + p0 + p8*8,
                 (char*)raw + 36864 + i*1024);
        }
    }
    __syncthreads();   // bar1: drains vmcnt(0) -> raw complete

    // ---- T: transpose raw -> At1/At2 ----
    {
        const int sthr = tid & 255;
        const int co = sthr>>3, po = sthr&7;
        u32 W[8][4];
        if (tid >= 256) {
            // emb chunk co: channels 8co..8co+7
            u32 R[8][4];
#pragma unroll
            for (int j=0;j<8;j++)
                __builtin_memcpy(&R[j][0], raw + 18432 + (8*co+j)*64 + po*8, 16);
#pragma unroll
            for (int p=0;p<8;p++){
                const int u = p>>1, hf = p&1;
#pragma unroll
                for (int m=0;m<4;m++){
                    u32 A0 = R[2*m][u], A1 = R[2*m+1][u];
                    W[p][m] = hf ? ((A0>>16) | (A1 & 0xffff0000u))
                                 : ((A0 & 0xffffu) | (A1<<16));
                }
            }
#pragma unroll
            for (int p=0;p<8;p++){
                int pg = 8*po + p;
                __builtin_memcpy(At2 + pg*264 + ((co ^ swz(pg))<<3), &W[p][0], 16);
            }
        } else if (co >= 4) {
            // lo: cat chunk co = lo channels 8(co-4)..+7
            u32 R[8][4];
#pragma unroll
            for (int j=0;j<8;j++)
                __builtin_memcpy(&R[j][0], raw + (8*(co-4)+j)*64 + po*8, 16);
#pragma unroll
            for (int p=0;p<8;p++){
                const int u = p>>1, hf = p&1;
#pragma unroll
                for (int m=0;m<4;m++){
                    u32 A0 = R[2*m][u], A1 = R[2*m+1][u];
                    W[p][m] = hf ? ((A0>>16) | (A1 & 0xffff0000u))
                                 : ((A0 & 0xffffu) | (A1<<16));
                }
            }
#pragma unroll
            for (int p=0;p<8;p++){
                int pg = 8*po + p;
                __builtin_memcpy(At1 + pg*264 + ((co ^ swz(pg))<<3), &W[p][0], 16);
            }
        } else {
            // hi pixel-shuffle: cat ch c=8co+j <- raw_hi rows hc=c*4+h2 (even px), hc+1 (odd px)
            const int h2 = (h&1)*2;
            u32 E[8][2], O[8][2];
#pragma unroll
            for (int j=0;j<8;j++){
                int hc = (8*co+j)*4 + h2;
                __builtin_memcpy(&E[j][0], raw + 14336 + hc*32 + po*4, 8);
                __builtin_memcpy(&O[j][0], raw + 14336 + (hc+1)*32 + po*4, 8);
            }
#pragma unroll
            for (int p=0;p<8;p++){
                const int k = p>>1, u = k>>1, hf = k&1;
#pragma unroll
                for (int m=0;m<4;m++){
                    u32 A0, A1;
                    if (p&1){ A0 = O[2*m][u]; A1 = O[2*m+1][u]; }
                    else    { A0 = E[2*m][u]; A1 = E[2*m+1][u]; }
                    W[p][m] = hf ? ((A0>>16) | (A1 & 0xffff0000u))
                                 : ((A0 & 0xffffu) | (A1<<16));
                }
            }
#pragma unroll
            for (int p=0;p<8;p++){
                int pg = 8*po + p;
                __builtin_memcpy(At1 + pg*264 + ((co ^ swz(pg))<<3), &W[p][0], 16);
            }
        }
    }
    __syncthreads();   // bar2: At1 + At2 ready

    // ---- P1: reduce + mix (both parts), per-wave (pt, ks) ----
    const int pt = wvi>>2, ks = wvi&3;
    const int pp = pt*32 + col, sw = swz(pp);
    const u16* arow1 = At1 + pp*264;
    const u16* arow2 = At2 + pp*264;

    f32x16 racc, macc;
#pragma unroll
    for (int r=0;r<16;r++){ racc[r]=0.f; macc[r]=0.f; }

    short8 Wf[4], Be2[4];
#pragma unroll
    for (int t4=0;t4<4;t4++)
        __builtin_memcpy(&Wf[t4], weffB + (size_t)col*256 + (4*ks+t4)*16 + q*8, 16);
#pragma unroll
    for (int t4=0;t4<4;t4++)
        __builtin_memcpy(&Be2[t4], embB + (size_t)col*256 + (4*ks+t4)*16 + q*8, 16);

#pragma unroll
    for (int bt=0; bt<4; bt++){
        short8 Bb[4];
#pragma unroll
        for (int si=0;si<4;si++)
            __builtin_memcpy(&Bb[si], rwB + (((size_t)(ks*16 + bt*4 + si))*64 + lane)*8, 16);
#pragma unroll
        for (int si=0;si<4;si++){
            int s = bt*4 + si;
            short8 a; __builtin_memcpy(&a, arow1 + (((2*s+q)^sw)<<3), 16);
            racc = __builtin_amdgcn_mfma_f32_32x32x16_bf16(a, Bb[si], racc, 0,0,0);
            int d = s - 4*ks;
            if (d>=0 && d<4)
                macc = __builtin_amdgcn_mfma_f32_32x32x16_bf16(a, Wf[d], macc, 0,0,0);
        }
    }
#pragma unroll
    for (int t4=0;t4<4;t4++){
        int t = 4*ks + t4;
        short8 a; __builtin_memcpy(&a, arow2 + (((2*t+q)^sw)<<3), 16);
        macc = __builtin_amdgcn_mfma_f32_32x32x16_bf16(a, Be2[t4], macc, 0,0,0);
    }
    {
        int oc = ks*32 + col;
        float bias = wf[RED_B + oc];
#pragma unroll
        for (int r=0;r<16;r++){
            int row = (r&3) + 8*(r>>2) + 4*q;
            cat2[((size_t)(gpx + pt*32 + row))*128 + oc] = f2bf(racc[r] + bias);
        }
    }

    // ---- P4: combine 4 K-partials via raw-as-f32 exch (raw dead after bar2) ----
    float* exch = (float*)raw;
    if (ks != 0){
#pragma unroll
        for (int r=0;r<16;r++){
            int row = (r&3) + 8*(r>>2) + 4*q;
            exch[pt*3072 + (ks-1)*1024 + row*32 + col] = macc[r];
        }
    }
    __syncthreads();   // bar3
    if (ks == 0){
        float bias = wf[C1E_B + col];
#pragma unroll
        for (int r=0;r<16;r++){
            int row = (r&3) + 8*(r>>2) + 4*q;
            int base = pt*3072 + row*32 + col;
            float v = macc[r] + exch[base] + exch[base+1024] + exch[base+2048] + bias;
            mixt[((size_t)(gpx + pt*32 + row))*32 + col] = f2bf(lrelu(v));
        }
    }
}

// ---------------- fp32 (dead-path) fused reduce+mix: round-7 reg-staged body ----------------
template<int M>
__device__ __forceinline__ void rm_body_reg(
    const void* __restrict__ hi, const void* __restrict__ lo, const void* __restrict__ emb,
    const u16* __restrict__ rwB, const u16* __restrict__ weffB, const u16* __restrict__ embB,
    const float* __restrict__ wf, u16* __restrict__ cat2, u16* __restrict__ mixt,
    u16* At)
{
    const int tid = threadIdx.x, wvi = tid>>6, lane = tid&63;
    const int col = lane&31, q = lane>>5;
    const int gpx = blockIdx.x*64;
    const int b = gpx>>14, p0 = gpx&16383;
    const int h = p0>>7, w0 = p0&127;

    const int sthr = tid & 255;
    const int co = sthr>>3, po = sthr&7;
    const bool is_emb = tid >= 256;

    u32 Wreg[8][4];

    if (is_emb) {
        u32 R[8][4];
        size_t base = ((size_t)(b*256 + 8*co))*HW + p0 + 8*po;
        float raw[8][8];
#pragma unroll
        for (int j=0;j<8;j++)
            __builtin_memcpy(&raw[j][0], (const float*)emb + base + (size_t)j*HW, 32);
#pragma unroll
        for (int j=0;j<8;j++)
#pragma unroll
        for (int m=0;m<4;m++) R[j][m] = pk2(raw[j][2*m], raw[j][2*m+1]);
#pragma unroll
        for (int p=0;p<8;p++){
            const int u = p>>1, hf = p&1;
#pragma unroll
            for (int m=0;m<4;m++){
                u32 A0 = R[2*m][u], A1 = R[2*m+1][u];
                Wreg[p][m] = hf ? ((A0>>16) | (A1 & 0xffff0000u))
                                : ((A0 & 0xffffu) | (A1<<16));
            }
        }
    } else {
        u32 W[8][4];
        if (co < 28) {
            u32 R[8][4];
            size_t base = ((size_t)(b*224 + 8*co))*HW + p0 + 8*po;
            float raw[8][8];
#pragma unroll
            for (int j=0;j<8;j++)
                __builtin_memcpy(&raw[j][0], (const float*)lo + base + (size_t)j*HW, 32);
#pragma unroll
            for (int j=0;j<8;j++)
#pragma unroll
            for (int m=0;m<4;m++) R[j][m] = pk2(raw[j][2*m], raw[j][2*m+1]);
#pragma unroll
            for (int p=0;p<8;p++){
                const int u = p>>1, hf = p&1;
#pragma unroll
                for (int m=0;m<4;m++){
                    u32 A0 = R[2*m][u], A1 = R[2*m+1][u];
                    W[p][m] = hf ? ((A0>>16) | (A1 & 0xffff0000u))
                                 : ((A0 & 0xffffu) | (A1<<16));
                }
            }
            const int ch = co + 4;
#pragma unroll
            for (int p=0;p<8;p++){
                int pg = 8*po + p;
                __builtin_memcpy(At + pg*264 + ((ch ^ swz(pg))<<3), &W[p][0], 16);
            }
        } else {
            const int cc0 = (co-28)*8, h2 = (h&1)*2;
            u32 E[8][2], O[8][2];
            float rE[8][4], rO[8][4];
#pragma unroll
            for (int j=0;j<8;j++){
                int hc = (cc0+j)*4 + h2;
                size_t src = ((size_t)(b*128 + hc))*4096 + (size_t)(h>>1)*64 + (w0>>1) + 4*po;
                __builtin_memcpy(&rE[j][0], (const float*)hi + src, 16);
                __builtin_memcpy(&rO[j][0], (const float*)hi + src + 4096, 16);
            }
#pragma unroll
            for (int j=0;j<8;j++){
                E[j][0] = pk2(rE[j][0], rE[j][1]); E[j][1] = pk2(rE[j][2], rE[j][3]);
                O[j][0] = pk2(rO[j][0], rO[j][1]); O[j][1] = pk2(rO[j][2], rO[j][3]);
            }
#pragma unroll
            for (int p=0;p<8;p++){
                const int k = p>>1, u = k>>1, hf = k&1;
#pragma unroll
                for (int m=0;m<4;m++){
                    u32 A0, A1;
                    if (p&1){ A0 = O[2*m][u]; A1 = O[2*m+1][u]; }
                    else    { A0 = E[2*m][u]; A1 = E[2*m+1][u]; }
                    W[p][m] = hf ? ((A0>>16) | (A1 & 0xffff0000u))
                                 : ((A0 & 0xffffu) | (A1<<16));
                }
            }
            const int ch = co - 28;
#pragma unroll
            for (int p=0;p<8;p++){
                int pg = 8*po + p;
                __builtin_memcpy(At + pg*264 + ((ch ^ swz(pg))<<3), &W[p][0], 16);
            }
        }
    }
    __syncthreads();

    const int pt = wvi>>2, ks = wvi&3;
    const int pp = pt*32 + col, sw = swz(pp);
    const u16* arow = At + pp*264;

    f32x16 racc, macc;
#pragma unroll
    for (int r=0;r<16;r++){ racc[r]=0.f; macc[r]=0.f; }

    short8 Wf[4];
#pragma unroll
    for (int t4=0;t4<4;t4++)
        __builtin_memcpy(&Wf[t4], weffB + (size_t)col*256 + (4*ks+t4)*16 + q*8, 16);

#pragma unroll
    for (int bt=0; bt<4; bt++){
        short8 Bb[4];
#pragma unroll
        for (int si=0;si<4;si++)
            __builtin_memcpy(&Bb[si], rwB + (((size_t)(ks*16 + bt*4 + si))*64 + lane)*8, 16);
#pragma unroll
        for (int si=0;si<4;si++){
            int s = bt*4 + si;
            short8 a; __builtin_memcpy(&a, arow + (((2*s+q)^sw)<<3), 16);
            racc = __builtin_amdgcn_mfma_f32_32x32x16_bf16(a, Bb[si], racc, 0,0,0);
            int d = s - 4*ks;
            if (d>=0 && d<4)
                macc = __builtin_amdgcn_mfma_f32_32x32x16_bf16(a, Wf[d], macc, 0,0,0);
        }
    }
    {
        int oc = ks*32 + col;
        float bias = wf[RED_B + oc];
#pragma unroll
        for (int r=0;r<16;r++){
            int row = (r&3) + 8*(r>>2) + 4*q;
            cat2[((size_t)(gpx + pt*32 + row))*128 + oc] = f2bf(racc[r] + bias);
        }
    }
    __syncthreads();

    if (is_emb){
#pragma unroll
        for (int p=0;p<8;p++){
            int pg = 8*po + p;
            __builtin_memcpy(At + pg*264 + ((co ^ swz(pg))<<3), &Wreg[p][0], 16);
        }
    }
    __syncthreads();

    {
        short8 Be[4];
#pragma unroll
        for (int t4=0;t4<4;t4++)
            __builtin_memcpy(&Be[t4], embB + (size_t)col*256 + (4*ks+t4)*16 + q*8, 16);
#pragma unroll
        for (int t4=0;t4<4;t4++){
            int t = 4*ks + t4;
            short8 a; __builtin_memcpy(&a, arow + (((2*t+q)^sw)<<3), 16);
            macc = __builtin_amdgcn_mfma_f32_32x32x16_bf16(a, Be[t4], macc, 0,0,0);
        }
    }
    __syncthreads();

    float* exch = (float*)At;
    if (ks != 0){
#pragma unroll
        for (int r=0;r<16;r++){
            int row = (r&3) + 8*(r>>2) + 4*q;
            exch[pt*3072 + (ks-1)*1024 + row*32 + col] = macc[r];
        }
    }
    __syncthreads();
    if (ks == 0){
        float bias = wf[C1E_B + col];
#pragma unroll
        for (int r=0;r<16;r++){
            int row = (r&3) + 8*(r>>2) + 4*q;
            int base = pt*3072 + row*32 + col;
            float v = macc[r] + exch[base] + exch[base+1024] + exch[base+2048] + bias;
            mixt[((size_t)(gpx + pt*32 + row))*32 + col] = f2bf(lrelu(v));
        }
    }
}

__global__ __launch_bounds__(512,4) void k_rmf(
    const void* __restrict__ hi, const void* __restrict__ lo, const void* __restrict__ emb,
    const u16* __restrict__ rwB, const u16* __restrict__ weffB, const u16* __restrict__ embB,
    const float* __restrict__ wf, u16* __restrict__ cat2, u16* __restrict__ mixt,
    const u32* __restrict__ flag)
{
    if (*flag != 0u) return;
    __shared__ u16 At[64*264];
    rm_body_reg<0>(hi, lo, emb, rwB, weffB, embB, wf, cat2, mixt, At);
}

// ---------------- fused conv2 + involution + out conv + BN + lrelu ----------------
template<int M>
__device__ __forceinline__ void inv_body(
    const u16* __restrict__ cat2, const u16* __restrict__ mixt,
    const u16* __restrict__ c2B, const u16* __restrict__ outB,
    const float* __restrict__ wf, void* __restrict__ out,
    u16* halo_m, u16* wgt_l, u16* halo_c, u16* og)
{
    const int tid = threadIdx.x, wvi = tid>>6, lane = tid&63;
    const int col = lane&31, q = lane>>5;
    const int b = blockIdx.y, ty = blockIdx.x>>3, tx = blockIdx.x&7;
    const int py = tid>>4, px = tid&15;

    f32x16 acc[2][2];
#pragma unroll
    for (int i=0;i<2;i++)
#pragma unroll
    for (int j=0;j<2;j++)
#pragma unroll
    for (int r=0;r<16;r++) acc[i][j][r] = 0.f;

#pragma unroll
    for (int i=0;i<6;i++){
        int idx = tid + i*256;
        if (idx < 1296){
            int point = idx>>2, cq = idx&3;
            int y = ty*16 + point/18 - 1, x = tx*16 + point%18 - 1;
            short8 v;
            if (y>=0 && y<128 && x>=0 && x<128)
                __builtin_memcpy(&v, mixt + ((size_t)(b*HW + y*128 + x))*32 + cq*8, 16);
            else { short z=0; v = (short8){z,z,z,z,z,z,z,z}; }
            *(short8*)(halo_m + point*40 + cq*8) = v;
        }
    }
    __syncthreads();

#pragma unroll 1
    for (int g=0; g<8; g++){
        __syncthreads();

        const int o = g*25 + col;
        short8 Bf[18];
#pragma unroll
        for (int s=0;s<18;s++)
            __builtin_memcpy(&Bf[s], c2B + (size_t)o*288 + s*16 + q*8, 16);

#pragma unroll
        for (int i=0;i<4;i++){
            int idx = tid + i*256;
            if (idx < 800){
                int point = idx>>1, cq = idx&1;
                int y = ty*16 + point/20 - 2, x = tx*16 + point%20 - 2;
                short8 v;
                if (y>=0 && y<128 && x>=0 && x<128)
                    __builtin_memcpy(&v, cat2 + ((size_t)(b*HW + y*128 + x))*128 + g*16 + cq*8, 16);
                else { short z=0; v = (short8){z,z,z,z,z,z,z,z}; }
                *(short8*)(halo_c + point*16 + cq*8) = v;
            }
        }

        f32x16 c0, c1;
#pragma unroll
        for (int r=0;r<16;r++){ c0[r]=0.f; c1[r]=0.f; }
        const int p0 = wvi*64 + col, p1 = p0 + 32;
        const int pya = p0>>4, pxa = p0&15, pyb = p1>>4, pxb = p1&15;
#pragma unroll
        for (int s=0;s<18;s++){
            int tap = s>>1, ih = s&1;
            int dy = tap/3, dx = tap%3;
            short8 a0, a1;
            __builtin_memcpy(&a0, halo_m + ((pya+dy)*18 + pxa+dx)*40 + ih*16 + q*8, 16);
            __builtin_memcpy(&a1, halo_m + ((pyb+dy)*18 + pxb+dx)*40 + ih*16 + q*8, 16);
            c0 = __builtin_amdgcn_mfma_f32_32x32x16_bf16(a0, Bf[s], c0, 0,0,0);
            c1 = __builtin_amdgcn_mfma_f32_32x32x16_bf16(a1, Bf[s], c1, 0,0,0);
        }
        {
            float bias = wf[C2_B + o];
#pragma unroll
            for (int rt2=0; rt2<2; rt2++){
                int mb = wvi*64 + rt2*32;
#pragma unroll
                for (int r=0;r<16;r+=2){
                    int row0 = (r&3) + 8*(r>>2) + 4*q;
                    float v0 = (rt2 ? c1[r]   : c0[r])   + bias;
                    float v1 = (rt2 ? c1[r+1] : c0[r+1]) + bias;
                    u32 pkv = (u32)f2bf(v0) | ((u32)f2bf(v1)<<16);
                    *(u32*)(wgt_l + (size_t)col*264 + mb + row0) = pkv;
                }
            }
        }
        __syncthreads();

        float wvv[25];
#pragma unroll
        for (int t=0;t<25;t++) wvv[t] = bf2f(wgt_l[t*264 + tid]);

        float a16[16];
#pragma unroll
        for (int cc=0;cc<16;cc++) a16[cc]=0.f;
#pragma unroll
        for (int t=0;t<25;t++){
            int dy = t/5, dx = t%5;
            u32 vv[8];
            __builtin_memcpy(vv, halo_c + ((py+dy)*20 + px+dx)*16, 32);
            float wt = wvv[t];
#pragma unroll
            for (int r=0;r<8;r++){
                u32 u = vv[r];
                u32 ulo = u<<16, uhi = u & 0xffff0000u;
                float x0, x1;
                __builtin_memcpy(&x0,&ulo,4); __builtin_memcpy(&x1,&uhi,4);
                a16[2*r]   += wt*x0;
                a16[2*r+1] += wt*x1;
            }
        }
        u32 pk[8];
#pragma unroll
        for (int r=0;r<8;r++) pk[r] = (u32)f2bf(a16[2*r]) | ((u32)f2bf(a16[2*r+1])<<16);
        __builtin_memcpy(og + tid*16, pk, 32);
        __syncthreads();

        short8 bo0, bo1;
        __builtin_memcpy(&bo0, outB + (size_t)(col)*128      + g*16 + q*8, 16);
        __builtin_memcpy(&bo1, outB + (size_t)(32+col)*128   + g*16 + q*8, 16);
#pragma unroll
        for (int rt2=0; rt2<2; rt2++){
            int prow = (wvi*2 + rt2)*32 + col;
            short8 a; __builtin_memcpy(&a, og + prow*16 + q*8, 16);
            acc[rt2][0] = __builtin_amdgcn_mfma_f32_32x32x16_bf16(a, bo0, acc[rt2][0], 0,0,0);
            acc[rt2][1] = __builtin_amdgcn_mfma_f32_32x32x16_bf16(a, bo1, acc[rt2][1], 0,0,0);
        }
    }
#pragma unroll
    for (int rt2=0; rt2<2; rt2++)
#pragma unroll
    for (int nt=0; nt<2; nt++){
        int oc = nt*32 + col;
        float bias = wf[OUT_B+oc], sc = wf[BN_SC+oc], sh = wf[BN_SH+oc];
#pragma unroll
        for (int r=0;r<16;r++){
            int row = (r&3) + 8*(r>>2) + 4*q;
            int p = (wvi*2 + rt2)*32 + row;
            int yy = ty*16 + (p>>4), xx = tx*16 + (p&15);
            float v = lrelu((acc[rt2][nt][r] + bias)*sc + sh);
            size_t oidx = ((size_t)(b*64 + oc))*HW + yy*128 + xx;
            if (M==1) ((u16*)out)[oidx] = f2bf(v);
            else ((float*)out)[oidx] = v;
        }
    }
}

__global__ __launch_bounds__(256,2) void k_inv(
    const u16* __restrict__ cat2, const u16* __restrict__ mixt,
    const u16* __restrict__ c2B, const u16* __restrict__ outB,
    const float* __restrict__ wf, void* __restrict__ out, const u32* __restrict__ flag)
{
    __shared__ u16 halo_m[324*40];
    __shared__ u16 wgt_l[32*264];
    __shared__ u16 halo_c[400*16];
    __shared__ u16 og[256*16];
    if (*flag) inv_body<1>(cat2, mixt, c2B, outB, wf, out, halo_m, wgt_l, halo_c, og);
    else       inv_body<0>(cat2, mixt, c2B, outB, wf, out, halo_m, wgt_l, halo_c, og);
}

extern "C" void kernel_launch(void* const* d_in, const int* in_sizes, int n_in,
                              void* d_out, int out_size, void* d_ws, size_t ws_size,
                              hipStream_t stream) {
    const void* hi  = d_in[0];
    const void* lo  = d_in[1];
    const void* emb = d_in[2];
    char* ws = (char*)d_ws;
    float* wf = (float*)ws;
    u32* flag = (u32*)(ws + FLAG_OFF);
    u16* cat2 = (u16*)(ws + CAT2_OFF);
    u16* mixt = (u16*)(ws + MIX_OFF);

    detect_kernel<<<1, 64, 0, stream>>>(emb, flag);

    k_prep<<<531,256,0,stream>>>(d_in[3],d_in[4],d_in[5],d_in[6],d_in[7],d_in[8],
        d_in[9],d_in[10],d_in[11],d_in[12],d_in[13],d_in[14],d_in[15],d_in[16], ws, flag);

    k_rm<<<2048,512,0,stream>>>(hi, lo, emb, (const u16*)(ws+RWB_OFF),
                                (const u16*)(ws+WEFF_OFF), (const u16*)(ws+EMBB_OFF),
                                wf, cat2, mixt, flag);
    k_rmf<<<2048,512,0,stream>>>(hi, lo, emb, (const u16*)(ws+RWB_OFF),
                                 (const u16*)(ws+WEFF_OFF), (const u16*)(ws+EMBB_OFF),
                                 wf, cat2, mixt, flag);

    k_inv<<<dim3(64,8),256,0,stream>>>(cat2, mixt, (const u16*)(ws+C2PB_OFF),
                                       (const u16*)(ws+OUTB_OFF), wf, d_out, flag);
}

// Round 9
// 428.752 us; speedup vs baseline: 1.0055x; 1.0055x over previous
//
#include <hip/hip_runtime.h>

typedef unsigned short u16; typedef unsigned int u32; typedef unsigned long long u64;
typedef __attribute__((ext_vector_type(8))) short short8;
typedef __attribute__((ext_vector_type(16))) float f32x16;

#define HW 16384

// fp32 ws region (float index)
#define RED_B  0
#define C1E_B  128
#define C2_B   160
#define OUT_B  416
#define BN_SC  480
#define BN_SH  544
// byte offsets in ws
#define FLAG_OFF   4096
#define RWB_OFF    8192      // bf16 reduce weights, fragment-major [otile(4)][s(16)][lane(64)][8]
#define C1B_OFF    73728     // bf16 [32][128]
#define EMBB_OFF   81920     // bf16 [32][256]
#define OUTB_OFF   98304     // bf16 [64][128]
#define C2PB_OFF   114688    // bf16 [256][288] tap-major (zeros for oc>=200)
#define WEFF_OFF   262144    // bf16 [32][256] = conv1 @ W_red
#define CAT2_OFF   524288    // bf16 [8*16384][128] pixel-major
#define MIX_OFF    34078720  // bf16 [8*16384][32]  pixel-major

__device__ __forceinline__ float bf2f(u16 x){ u32 u=((u32)x)<<16; float f; __builtin_memcpy(&f,&u,4); return f; }
__device__ __forceinline__ u16 f2bf(float f){ u32 u; __builtin_memcpy(&u,&f,4); return (u16)((u + 0x7fffu + ((u>>16)&1u))>>16); }
__device__ __forceinline__ u32 pk2(float a, float b){ return (u32)f2bf(a) | ((u32)f2bf(b)<<16); }
__device__ __forceinline__ float lrelu(float x){ return x>0.f ? x : 0.01f*x; }

template<int M> __device__ __forceinline__ u16 ldb(const void* p, size_t i){
    if (M==1) return ((const u16*)p)[i];
    return f2bf(((const float*)p)[i]);
}
template<int M> __device__ __forceinline__ float ldf(const void* p, size_t i){
    if (M==1) return bf2f(((const u16*)p)[i]);
    return ((const float*)p)[i];
}
// bijective swizzle over pixel-octet AND pixel-within-octet
__device__ __forceinline__ int swz(int p){ return ((p>>1) ^ (p>>3)) & 7; }

// async global->LDS, 16B per lane: LDS dest = uniform base + lane*16; global src per-lane
__device__ __forceinline__ void gl16(const void* g, void* l){
    __builtin_amdgcn_global_load_lds(
        (const __attribute__((address_space(1))) u32*)g,
        (__attribute__((address_space(3))) u32*)l, 16, 0, 0);
}

// ---------------- dtype detector ----------------
__global__ void detect_kernel(const void* __restrict__ emb, u32* __restrict__ flag){
    int tid = threadIdx.x;
    const u16* p = (const u16*)emb;
    int e = (p[tid*2] >> 7) & 0xFF;
    u64 m = __ballot(e >= 100 && e <= 140);
    if (tid == 0) *flag = (__popcll(m) >= 32) ? 1u : 0u;
}

// ---------------- prep ----------------
template<int M>
__device__ __forceinline__ void prep_body(
    const void* rw, const void* rb, const void* c1w, const void* c1b,
    const void* c2w, const void* c2b, const void* ew, const void* eb,
    const void* ow, const void* ob, const void* gam, const void* bet,
    const void* mn, const void* vr, char* ws)
{
    float* wf = (float*)ws;
    int i = blockIdx.x*256 + threadIdx.x;
    if (i < 32768) {
        int o = i>>8, ic = i&255;
        int s = ic>>4, qq = (ic>>3)&1, e = ic&7;
        int dst = (((o>>5)*16 + s)*64 + qq*32 + (o&31))*8 + e;
        ((u16*)(ws+RWB_OFF))[dst] = ldb<M>(rw, i);
    }
    else if (i < 36864)  ((u16*)(ws+C1B_OFF))[i-32768] = ldb<M>(c1w, i-32768);
    else if (i < 45056)  ((u16*)(ws+EMBB_OFF))[i-36864] = ldb<M>(ew, i-36864);
    else if (i < 53248)  ((u16*)(ws+OUTB_OFF))[i-45056] = ldb<M>(ow, i-45056);
    else if (i < 126976) {
        int j = i-53248; int o = j/288, k = j - o*288;
        int tap = k>>5, ic = k&31;
        u16 v = 0;
        if (o < 200) v = ldb<M>(c2w, (size_t)o*288 + ic*9 + tap);
        ((u16*)(ws+C2PB_OFF))[j] = v;
    }
    else if (i < 127584) {
        int j = i-126976;
        if (j < 128) wf[RED_B+j] = ldf<M>(rb, j);
        else if (j < 160) {
            int o = j-128;
            float s = ldf<M>(c1b,o) + ldf<M>(eb,o);
#pragma unroll 8
            for (int ic=0; ic<128; ic++)
                s += ldf<M>(c1w, (size_t)o*128+ic) * ldf<M>(rb, ic);
            wf[C1E_B+o] = s;
        }
        else if (j < 416) { int o = j-160; wf[C2_B+o] = (o<200) ? ldf<M>(c2b,o) : 0.f; }
        else if (j < 480) wf[OUT_B+j-416] = ldf<M>(ob, j-416);
        else if (j < 544) { int c=j-480; wf[BN_SC+c] = ldf<M>(gam,c) * rsqrtf(ldf<M>(vr,c)+1e-5f); }
        else { int c=j-544; wf[BN_SH+c] = ldf<M>(bet,c) - ldf<M>(mn,c)*ldf<M>(gam,c)*rsqrtf(ldf<M>(vr,c)+1e-5f); }
    }
    else if (i < 135776) {
        int j = i - 127584; int oc = j>>8, k2 = j&255;
        float s = 0.f;
#pragma unroll 8
        for (int ic=0; ic<128; ic++)
            s += ldf<M>(c1w, (size_t)oc*128+ic) * ldf<M>(rw, (size_t)ic*256+k2);
        ((u16*)(ws+WEFF_OFF))[oc*256+k2] = f2bf(s);
    }
}

__global__ __launch_bounds__(256) void k_prep(
    const void* rw, const void* rb, const void* c1w, const void* c1b,
    const void* c2w, const void* c2b, const void* ew, const void* eb,
    const void* ow, const void* ob, const void* gam, const void* bet,
    const void* mn, const void* vr, char* ws, const u32* __restrict__ flag)
{
    if (*flag) prep_body<1>(rw,rb,c1w,c1b,c2w,c2b,ew,eb,ow,ob,gam,bet,mn,vr,ws);
    else       prep_body<0>(rw,rb,c1w,c1b,c2w,c2b,ew,eb,ow,ob,gam,bet,mn,vr,ws);
}

// fp32 LDS-rows transpose half: 4 channels (jh half) x 8 px -> 8B At slots
// raw rows are 64 floats; source was staged with px-quad XOR (i&15); read undoes it.
__device__ __forceinline__ void trans_half_f32(
    const float* rowbase, int rstart, int po, int jh, u16* At, int chunkIdx)
{
    u32 R2[4][4];
#pragma unroll
    for (int jp=0;jp<4;jp++){
        int r = rstart + 4*jh + jp;
        int v = (r>>2)&15;
        float fa[4], fb[4];
        __builtin_memcpy(fa, rowbase + r*64 + ((2*po)^v)*4, 16);
        __builtin_memcpy(fb, rowbase + r*64 + ((2*po+1)^v)*4, 16);
        R2[jp][0]=pk2(fa[0],fa[1]); R2[jp][1]=pk2(fa[2],fa[3]);
        R2[jp][2]=pk2(fb[0],fb[1]); R2[jp][3]=pk2(fb[2],fb[3]);
    }
#pragma unroll
    for (int p=0;p<8;p++){
        const int u=p>>1, hf=p&1;
        u32 Wh[2];
#pragma unroll
        for (int mp=0;mp<2;mp++){
            u32 A0=R2[2*mp][u], A1=R2[2*mp+1][u];
            Wh[mp] = hf ? ((A0>>16)|(A1&0xffff0000u)) : ((A0&0xffffu)|(A1<<16));
        }
        int pg = 8*po+p;
        __builtin_memcpy(At + pg*264 + ((chunkIdx ^ swz(pg))<<3) + jh*4, Wh, 8);
    }
}

// ---------------- fp32 (LIVE) fused reduce+mix: async gload_lds staging ----------------
// grid 2048, 512 thr. LDS 107.5 KB (raw 73.7 + At 33.8), time-multiplexed:
//  S1 lo+hi -> rawf (async, zero-VGPR)            [bar1]
//  T1 rawf -> At (concat, fp32->bf16)             [bar2]
//  S2 emb -> rawf (async; overlaps P1a)
//  P1a reduce 16 MFMA + mix-partial 4 MFMA (At)  -> cat2
//                                                 [bar3: drains emb]
//  T2 rawf -> At (emb)                            [bar4]
//  P1b mix emb 4 MFMA (At); exch via rawf         [bar5] -> mixt
__global__ __launch_bounds__(512) void k_rmf(
    const void* __restrict__ hi, const void* __restrict__ lo, const void* __restrict__ emb,
    const u16* __restrict__ rwB, const u16* __restrict__ weffB, const u16* __restrict__ embB,
    const float* __restrict__ wf, u16* __restrict__ cat2, u16* __restrict__ mixt,
    const u32* __restrict__ flag)
{
    if (*flag != 0u) return;
    __shared__ float rawf[18432];   // 73728 B: lo[224][64] @0 | hi[128][32] @14336f ; later emb[256][64]; later f32 exch
    __shared__ u16 At[64*264];      // 33792 B: concat, then emb

    const int tid = threadIdx.x, wvi = tid>>6, lane = tid&63;
    const int col = lane&31, q = lane>>5;
    const int gpx = blockIdx.x*64;
    const int b = gpx>>14, p0 = gpx&16383;
    const int h = p0>>7, w0 = p0&127;

    // ---- S1: async lo (56 chunks) + hi (16 chunks); px-quad XOR on the SRC ----
    for (int i=wvi; i<56; i+=8){
        int r = 4*i + (lane>>4);
        int qd = (lane&15) ^ (i&15);
        gl16((const float*)lo + ((size_t)(b*224 + r))*HW + p0 + qd*4,
             (char*)rawf + i*1024);
    }
    for (int i=wvi; i<16; i+=8){
        int hc = 8*i + (lane>>3);
        int qd = (lane&7) ^ (i&7);
        gl16((const float*)hi + ((size_t)(b*128 + hc))*4096 + (size_t)(h>>1)*64 + (w0>>1) + qd*4,
             (char*)rawf + 57344 + i*1024);
    }
    __syncthreads();   // bar1: lo+hi landed

    // ---- T1: 512 thr: co=tid>>4 (chunk), po=(tid>>1)&7, jh=tid&1 ----
    {
        const int co = tid>>4, po = (tid>>1)&7, jh = tid&1;
        if (co >= 4) {
            trans_half_f32(rawf, 8*(co-4), po, jh, At, co);
        } else {
            const int h2 = (h&1)*2;
            u32 E2[4][2], O2[4][2];
#pragma unroll
            for (int jp=0;jp<4;jp++){
                int hc = (8*co + 4*jh + jp)*4 + h2;
                int slot = po ^ ((hc>>3)&7);
                float fe[4], fo[4];
                __builtin_memcpy(fe, rawf + 14336 + hc*32 + slot*4, 16);
                __builtin_memcpy(fo, rawf + 14336 + (hc+1)*32 + slot*4, 16);
                E2[jp][0]=pk2(fe[0],fe[1]); E2[jp][1]=pk2(fe[2],fe[3]);
                O2[jp][0]=pk2(fo[0],fo[1]); O2[jp][1]=pk2(fo[2],fo[3]);
            }
#pragma unroll
            for (int p=0;p<8;p++){
                const int k=p>>1, u=k>>1, hf=k&1;
                u32 Wh[2];
#pragma unroll
                for (int mp=0;mp<2;mp++){
                    u32 A0 = (p&1) ? O2[2*mp][u] : E2[2*mp][u];
                    u32 A1 = (p&1) ? O2[2*mp+1][u] : E2[2*mp+1][u];
                    Wh[mp] = hf ? ((A0>>16)|(A1&0xffff0000u)) : ((A0&0xffffu)|(A1<<16));
                }
                int pg = 8*po+p;
                __builtin_memcpy(At + pg*264 + ((co ^ swz(pg))<<3) + jh*4, Wh, 8);
            }
        }
    }
    __syncthreads();   // bar2: At(concat) ready; all rawf reads done

    // ---- S2: async emb -> rawf (reuse); latency hides under P1a ----
    for (int i=wvi; i<64; i+=8){
        int r = 4*i + (lane>>4);
        int qd = (lane&15) ^ (i&15);
        gl16((const float*)emb + ((size_t)(b*256 + r))*HW + p0 + qd*4,
             (char*)rawf + i*1024);
    }

    // ---- P1a: reduce + mix-partial, per-wave (pt, ks) ----
    const int pt = wvi>>2, ks = wvi&3;
    const int pp = pt*32 + col, sw = swz(pp);
    const u16* arow = At + pp*264;

    f32x16 racc, macc;
#pragma unroll
    for (int r=0;r<16;r++){ racc[r]=0.f; macc[r]=0.f; }

    short8 Wf[4];
#pragma unroll
    for (int t4=0;t4<4;t4++)
        __builtin_memcpy(&Wf[t4], weffB + (size_t)col*256 + (4*ks+t4)*16 + q*8, 16);

#pragma unroll
    for (int bt=0; bt<4; bt++){
        short8 Bb[4];
#pragma unroll
        for (int si=0;si<4;si++)
            __builtin_memcpy(&Bb[si], rwB + (((size_t)(ks*16 + bt*4 + si))*64 + lane)*8, 16);
#pragma unroll
        for (int si=0;si<4;si++){
            int s = bt*4 + si;
            short8 a; __builtin_memcpy(&a, arow + (((2*s+q)^sw)<<3), 16);
            racc = __builtin_amdgcn_mfma_f32_32x32x16_bf16(a, Bb[si], racc, 0,0,0);
            int d = s - 4*ks;
            if (d>=0 && d<4)
                macc = __builtin_amdgcn_mfma_f32_32x32x16_bf16(a, Wf[d], macc, 0,0,0);
        }
    }
    {
        int oc = ks*32 + col;
        float bias = wf[RED_B + oc];
#pragma unroll
        for (int r=0;r<16;r++){
            int row = (r&3) + 8*(r>>2) + 4*q;
            cat2[((size_t)(gpx + pt*32 + row))*128 + oc] = f2bf(racc[r] + bias);
        }
    }
    __syncthreads();   // bar3: emb landed; all At(concat) reads done

    // ---- T2: emb rawf -> At (overwrite) ----
    {
        const int co = tid>>4, po = (tid>>1)&7, jh = tid&1;
        trans_half_f32(rawf, 8*co, po, jh, At, co);
    }
    __syncthreads();   // bar4: At(emb) ready; all rawf(emb) reads done

    // ---- P1b: mix emb part ----
    {
        short8 Be[4];
#pragma unroll
        for (int t4=0;t4<4;t4++)
            __builtin_memcpy(&Be[t4], embB + (size_t)col*256 + (4*ks+t4)*16 + q*8, 16);
#pragma unroll
        for (int t4=0;t4<4;t4++){
            int t = 4*ks + t4;
            short8 a; __builtin_memcpy(&a, arow + (((2*t+q)^sw)<<3), 16);
            macc = __builtin_amdgcn_mfma_f32_32x32x16_bf16(a, Be[t4], macc, 0,0,0);
        }
    }

    // ---- P4: combine 4 K-partials via rawf-as-exch (rawf dead after bar4) ----
    float* exch = rawf;
    if (ks != 0){
#pragma unroll
        for (int r=0;r<16;r++){
            int row = (r&3) + 8*(r>>2) + 4*q;
            exch[pt*3072 + (ks-1)*1024 + row*32 + col] = macc[r];
        }
    }
    __syncthreads();   // bar5
    if (ks == 0){
        float bias = wf[C1E_B + col];
#pragma unroll
        for (int r=0;r<16;r++){
            int row = (r&3) + 8*(r>>2) + 4*q;
            int base = pt*3072 + row*32 + col;
            float v = macc[r] + exch[base] + exch[base+1024] + exch[base+2048] + bias;
            mixt[((size_t)(gpx + pt*32 + row))*32 + col] = f2bf(lrelu(v));
        }
    }
}

// ---------------- bf16 (dead-path) fused reduce+mix: round-8 async version ----------------
__global__ __launch_bounds__(512) void k_rm(
    const void* __restrict__ hi, const void* __restrict__ lo, const void* __restrict__ emb,
    const u16* __restrict__ rwB, const u16* __restrict__ weffB, const u16* __restrict__ embB,
    const float* __restrict__ wf, u16* __restrict__ cat2, u16* __restrict__ mixt,
    const u32* __restrict__ flag)
{
    if (*flag != 1u) return;
    __shared__ u16 At1[64*264];
    __shared__ u16 At2[64*264];
    __shared__ u16 raw[34816];

    const int tid = threadIdx.x, wvi = tid>>6, lane = tid&63;
    const int col = lane&31, q = lane>>5;
    const int gpx = blockIdx.x*64;
    const int b = gpx>>14, p0 = gpx&16383;
    const int h = p0>>7, w0 = p0&127;

    {
        for (int i=wvi; i<28; i+=8){
            int chunk = i*64 + lane;
            int ch = chunk>>3, p8 = chunk&7;
            gl16((const u16*)lo + ((size_t)(b*224+ch))*HW + p0 + p8*8,
                 (char*)raw + i*1024);
        }
        {
            int i = wvi;
            int chunk = i*64 + lane;
            int hc = chunk>>2, c4 = chunk&3;
            gl16((const u16*)hi + ((size_t)(b*128+hc))*4096 + (size_t)(h>>1)*64 + (w0>>1) + c4*8,
                 (char*)raw + 28672 + i*1024);
        }
        for (int i=wvi; i<32; i+=8){
            int chunk = i*64 + lane;
            int ch = chunk>>3, p8 = chunk&7;
            gl16((const u16*)emb + ((size_t)(b*256+ch))*HW + p0 + p8*8,
                 (char*)raw + 36864 + i*1024);
        }
    }
    __syncthreads();

    {
        const int sthr = tid & 255;
        const int co = sthr>>3, po = sthr&7;
        u32 W[8][4];
        if (tid >= 256) {
            u32 R[8][4];
#pragma unroll
            for (int j=0;j<8;j++)
                __builtin_memcpy(&R[j][0], raw + 18432 + (8*co+j)*64 + po*8, 16);
#pragma unroll
            for (int p=0;p<8;p++){
                const int u = p>>1, hf = p&1;
#pragma unroll
                for (int m=0;m<4;m++){
                    u32 A0 = R[2*m][u], A1 = R[2*m+1][u];
                    W[p][m] = hf ? ((A0>>16) | (A1 & 0xffff0000u))
                                 : ((A0 & 0xffffu) | (A1<<16));
                }
            }
#pragma unroll
            for (int p=0;p<8;p++){
                int pg = 8*po + p;
                __builtin_memcpy(At2 + pg*264 + ((co ^ swz(pg))<<3), &W[p][0], 16);
            }
        } else if (co >= 4) {
            u32 R[8][4];
#pragma unroll
            for (int j=0;j<8;j++)
                __builtin_memcpy(&R[j][0], raw + (8*(co-4)+j)*64 + po*8, 16);
#pragma unroll
            for (int p=0;p<8;p++){
                const int u = p>>1, hf = p&1;
#pragma unroll
                for (int m=0;m<4;m++){
                    u32 A0 = R[2*m][u], A1 = R[2*m+1][u];
                    W[p][m] = hf ? ((A0>>16) | (A1 & 0xffff0000u))
                                 : ((A0 & 0xffffu) | (A1<<16));
                }
            }
#pragma unroll
            for (int p=0;p<8;p++){
                int pg = 8*po + p;
                __builtin_memcpy(At1 + pg*264 + ((co ^ swz(pg))<<3), &W[p][0], 16);
            }
        } else {
            const int h2 = (h&1)*2;
            u32 E[8][2], O[8][2];
#pragma unroll
            for (int j=0;j<8;j++){
                int hc = (8*co+j)*4 + h2;
                __builtin_memcpy(&E[j][0], raw + 14336 + hc*32 + po*4, 8);
                __builtin_memcpy(&O[j][0], raw + 14336 + (hc+1)*32 + po*4, 8);
            }
#pragma unroll
            for (int p=0;p<8;p++){
                const int k = p>>1, u = k>>1, hf = k&1;
#pragma unroll
                for (int m=0;m<4;m++){
                    u32 A0, A1;
                    if (p&1){ A0 = O[2*m][u]; A1 = O[2*m+1][u]; }
                    else    { A0 = E[2*m][u]; A1 = E[2*m+1][u]; }
                    W[p][m] = hf ? ((A0>>16) | (A1 & 0xffff0000u))
                                 : ((A0 & 0xffffu) | (A1<<16));
                }
            }
#pragma unroll
            for (int p=0;p<8;p++){
                int pg = 8*po + p;
                __builtin_memcpy(At1 + pg*264 + ((co ^ swz(pg))<<3), &W[p][0], 16);
            }
        }
    }
    __syncthreads();

    const int pt = wvi>>2, ks = wvi&3;
    const int pp = pt*32 + col, sw = swz(pp);
    const u16* arow1 = At1 + pp*264;
    const u16* arow2 = At2 + pp*264;

    f32x16 racc, macc;
#pragma unroll
    for (int r=0;r<16;r++){ racc[r]=0.f; macc[r]=0.f; }

    short8 Wf[4], Be2[4];
#pragma unroll
    for (int t4=0;t4<4;t4++)
        __builtin_memcpy(&Wf[t4], weffB + (size_t)col*256 + (4*ks+t4)*16 + q*8, 16);
#pragma unroll
    for (int t4=0;t4<4;t4++)
        __builtin_memcpy(&Be2[t4], embB + (size_t)col*256 + (4*ks+t4)*16 + q*8, 16);

#pragma unroll
    for (int bt=0; bt<4; bt++){
        short8 Bb[4];
#pragma unroll
        for (int si=0;si<4;si++)
            __builtin_memcpy(&Bb[si], rwB + (((size_t)(ks*16 + bt*4 + si))*64 + lane)*8, 16);
#pragma unroll
        for (int si=0;si<4;si++){
            int s = bt*4 + si;
            short8 a; __builtin_memcpy(&a, arow1 + (((2*s+q)^sw)<<3), 16);
            racc = __builtin_amdgcn_mfma_f32_32x32x16_bf16(a, Bb[si], racc, 0,0,0);
            int d = s - 4*ks;
            if (d>=0 && d<4)
                macc = __builtin_amdgcn_mfma_f32_32x32x16_bf16(a, Wf[d], macc, 0,0,0);
        }
    }
#pragma unroll
    for (int t4=0;t4<4;t4++){
        int t = 4*ks + t4;
        short8 a; __builtin_memcpy(&a, arow2 + (((2*t+q)^sw)<<3), 16);
        macc = __builtin_amdgcn_mfma_f32_32x32x16_bf16(a, Be2[t4], macc, 0,0,0);
    }
    {
        int oc = ks*32 + col;
        float bias = wf[RED_B + oc];
#pragma unroll
        for (int r=0;r<16;r++){
            int row = (r&3) + 8*(r>>2) + 4*q;
            cat2[((size_t)(gpx + pt*32 + row))*128 + oc] = f2bf(racc[r] + bias);
        }
    }

    float* exch = (float*)raw;
    if (ks != 0){
#pragma unroll
        for (int r=0;r<16;r++){
            int row = (r&3) + 8*(r>>2) + 4*q;
            exch[pt*3072 + (ks-1)*1024 + row*32 + col] = macc[r];
        }
    }
    __syncthreads();
    if (ks == 0){
        float bias = wf[C1E_B + col];
#pragma unroll
        for (int r=0;r<16;r++){
            int row = (r&3) + 8*(r>>2) + 4*q;
            int base = pt*3072 + row*32 + col;
            float v = macc[r] + exch[base] + exch[base+1024] + exch[base+2048] + bias;
            mixt[((size_t)(gpx + pt*32 + row))*32 + col] = f2bf(lrelu(v));
        }
    }
}

// ---------------- fused conv2 + involution + out conv + BN + lrelu ----------------
template<int M>
__device__ __forceinline__ void inv_body(
    const u16* __restrict__ cat2, const u16* __restrict__ mixt,
    const u16* __restrict__ c2B, const u16* __restrict__ outB,
    const float* __restrict__ wf, void* __restrict__ out,
    u16* halo_m, u16* wgt_l, u16* halo_c, u16* og)
{
    const int tid = threadIdx.x, wvi = tid>>6, lane = tid&63;
    const int col = lane&31, q = lane>>5;
    const int b = blockIdx.y, ty = blockIdx.x>>3, tx = blockIdx.x&7;
    const int py = tid>>4, px = tid&15;

    f32x16 acc[2][2];
#pragma unroll
    for (int i=0;i<2;i++)
#pragma unroll
    for (int j=0;j<2;j++)
#pragma unroll
    for (int r=0;r<16;r++) acc[i][j][r] = 0.f;

#pragma unroll
    for (int i=0;i<6;i++){
        int idx = tid + i*256;
        if (idx < 1296){
            int point = idx>>2, cq = idx&3;
            int y = ty*16 + point/18 - 1, x = tx*16 + point%18 - 1;
            short8 v;
            if (y>=0 && y<128 && x>=0 && x<128)
                __builtin_memcpy(&v, mixt + ((size_t)(b*HW + y*128 + x))*32 + cq*8, 16);
            else { short z=0; v = (short8){z,z,z,z,z,z,z,z}; }
            *(short8*)(halo_m + point*40 + cq*8) = v;
        }
    }
    __syncthreads();

#pragma unroll 1
    for (int g=0; g<8; g++){
        __syncthreads();

        const int o = g*25 + col;
        short8 Bf[18];
#pragma unroll
        for (int s=0;s<18;s++)
            __builtin_memcpy(&Bf[s], c2B + (size_t)o*288 + s*16 + q*8, 16);

#pragma unroll
        for (int i=0;i<4;i++){
            int idx = tid + i*256;
            if (idx < 800){
                int point = idx>>1, cq = idx&1;
                int y = ty*16 + point/20 - 2, x = tx*16 + point%20 - 2;
                short8 v;
                if (y>=0 && y<128 && x>=0 && x<128)
                    __builtin_memcpy(&v, cat2 + ((size_t)(b*HW + y*128 + x))*128 + g*16 + cq*8, 16);
                else { short z=0; v = (short8){z,z,z,z,z,z,z,z}; }
                *(short8*)(halo_c + point*16 + cq*8) = v;
            }
        }

        f32x16 c0, c1;
#pragma unroll
        for (int r=0;r<16;r++){ c0[r]=0.f; c1[r]=0.f; }
        const int p0 = wvi*64 + col, p1 = p0 + 32;
        const int pya = p0>>4, pxa = p0&15, pyb = p1>>4, pxb = p1&15;
#pragma unroll
        for (int s=0;s<18;s++){
            int tap = s>>1, ih = s&1;
            int dy = tap/3, dx = tap%3;
            short8 a0, a1;
            __builtin_memcpy(&a0, halo_m + ((pya+dy)*18 + pxa+dx)*40 + ih*16 + q*8, 16);
            __builtin_memcpy(&a1, halo_m + ((pyb+dy)*18 + pxb+dx)*40 + ih*16 + q*8, 16);
            c0 = __builtin_amdgcn_mfma_f32_32x32x16_bf16(a0, Bf[s], c0, 0,0,0);
            c1 = __builtin_amdgcn_mfma_f32_32x32x16_bf16(a1, Bf[s], c1, 0,0,0);
        }
        {
            float bias = wf[C2_B + o];
#pragma unroll
            for (int rt2=0; rt2<2; rt2++){
                int mb = wvi*64 + rt2*32;
#pragma unroll
                for (int r=0;r<16;r+=2){
                    int row0 = (r&3) + 8*(r>>2) + 4*q;
                    float v0 = (rt2 ? c1[r]   : c0[r])   + bias;
                    float v1 = (rt2 ? c1[r+1] : c0[r+1]) + bias;
                    u32 pkv = (u32)f2bf(v0) | ((u32)f2bf(v1)<<16);
                    *(u32*)(wgt_l + (size_t)col*264 + mb + row0) = pkv;
                }
            }
        }
        __syncthreads();

        float wvv[25];
#pragma unroll
        for (int t=0;t<25;t++) wvv[t] = bf2f(wgt_l[t*264 + tid]);

        float a16[16];
#pragma unroll
        for (int cc=0;cc<16;cc++) a16[cc]=0.f;
#pragma unroll
        for (int t=0;t<25;t++){
            int dy = t/5, dx = t%5;
            u32 vv[8];
            __builtin_memcpy(vv, halo_c + ((py+dy)*20 + px+dx)*16, 32);
            float wt = wvv[t];
#pragma unroll
            for (int r=0;r<8;r++){
                u32 u = vv[r];
                u32 ulo = u<<16, uhi = u & 0xffff0000u;
                float x0, x1;
                __builtin_memcpy(&x0,&ulo,4); __builtin_memcpy(&x1,&uhi,4);
                a16[2*r]   += wt*x0;
                a16[2*r+1] += wt*x1;
            }
        }
        u32 pk[8];
#pragma unroll
        for (int r=0;r<8;r++) pk[r] = (u32)f2bf(a16[2*r]) | ((u32)f2bf(a16[2*r+1])<<16);
        __builtin_memcpy(og + tid*16, pk, 32);
        __syncthreads();

        short8 bo0, bo1;
        __builtin_memcpy(&bo0, outB + (size_t)(col)*128      + g*16 + q*8, 16);
        __builtin_memcpy(&bo1, outB + (size_t)(32+col)*128   + g*16 + q*8, 16);
#pragma unroll
        for (int rt2=0; rt2<2; rt2++){
            int prow = (wvi*2 + rt2)*32 + col;
            short8 a; __builtin_memcpy(&a, og + prow*16 + q*8, 16);
            acc[rt2][0] = __builtin_amdgcn_mfma_f32_32x32x16_bf16(a, bo0, acc[rt2][0], 0,0,0);
            acc[rt2][1] = __builtin_amdgcn_mfma_f32_32x32x16_bf16(a, bo1, acc[rt2][1], 0,0,0);
        }
    }
#pragma unroll
    for (int rt2=0; rt2<2; rt2++)
#pragma unroll
    for (int nt=0; nt<2; nt++){
        int oc = nt*32 + col;
        float bias = wf[OUT_B+oc], sc = wf[BN_SC+oc], sh = wf[BN_SH+oc];
#pragma unroll
        for (int r=0;r<16;r++){
            int row = (r&3) + 8*(r>>2) + 4*q;
            int p = (wvi*2 + rt2)*32 + row;
            int yy = ty*16 + (p>>4), xx = tx*16 + (p&15);
            float v = lrelu((acc[rt2][nt][r] + bias)*sc + sh);
            size_t oidx = ((size_t)(b*64 + oc))*HW + yy*128 + xx;
            if (M==1) ((u16*)out)[oidx] = f2bf(v);
            else ((float*)out)[oidx] = v;
        }
    }
}

__global__ __launch_bounds__(256,2) void k_inv(
    const u16* __restrict__ cat2, const u16* __restrict__ mixt,
    const u16* __restrict__ c2B, const u16* __restrict__ outB,
    const float* __restrict__ wf, void* __restrict__ out, const u32* __restrict__ flag)
{
    __shared__ u16 halo_m[324*40];
    __shared__ u16 wgt_l[32*264];
    __shared__ u16 halo_c[400*16];
    __shared__ u16 og[256*16];
    if (*flag) inv_body<1>(cat2, mixt, c2B, outB, wf, out, halo_m, wgt_l, halo_c, og);
    else       inv_body<0>(cat2, mixt, c2B, outB, wf, out, halo_m, wgt_l, halo_c, og);
}

extern "C" void kernel_launch(void* const* d_in, const int* in_sizes, int n_in,
                              void* d_out, int out_size, void* d_ws, size_t ws_size,
                              hipStream_t stream) {
    const void* hi  = d_in[0];
    const void* lo  = d_in[1];
    const void* emb = d_in[2];
    char* ws = (char*)d_ws;
    float* wf = (float*)ws;
    u32* flag = (u32*)(ws + FLAG_OFF);
    u16* cat2 = (u16*)(ws + CAT2_OFF);
    u16* mixt = (u16*)(ws + MIX_OFF);

    detect_kernel<<<1, 64, 0, stream>>>(emb, flag);

    k_prep<<<531,256,0,stream>>>(d_in[3],d_in[4],d_in[5],d_in[6],d_in[7],d_in[8],
        d_in[9],d_in[10],d_in[11],d_in[12],d_in[13],d_in[14],d_in[15],d_in[16], ws, flag);

    k_rmf<<<2048,512,0,stream>>>(hi, lo, emb, (const u16*)(ws+RWB_OFF),
                                 (const u16*)(ws+WEFF_OFF), (const u16*)(ws+EMBB_OFF),
                                 wf, cat2, mixt, flag);
    k_rm<<<2048,512,0,stream>>>(hi, lo, emb, (const u16*)(ws+RWB_OFF),
                                (const u16*)(ws+WEFF_OFF), (const u16*)(ws+EMBB_OFF),
                                wf, cat2, mixt, flag);

    k_inv<<<dim3(64,8),256,0,stream>>>(cat2, mixt, (const u16*)(ws+C2PB_OFF),
                                       (const u16*)(ws+OUTB_OFF), wf, d_out, flag);
}

// Round 10
// 417.794 us; speedup vs baseline: 1.0319x; 1.0262x over previous
//
#include <hip/hip_runtime.h>

typedef unsigned short u16; typedef unsigned int u32; typedef unsigned long long u64;
typedef __attribute__((ext_vector_type(8))) short short8;
typedef __attribute__((ext_vector_type(16))) float f32x16;

#define HW 16384

// fp32 ws region (float index)
#define RED_B  0
#define C1E_B  128
#define C2_B   160
#define OUT_B  416
#define BN_SC  480
#define BN_SH  544
// byte offsets in ws
#define FLAG_OFF   4096
#define RWB_OFF    8192      // bf16 reduce weights, fragment-major [otile(4)][s(16)][lane(64)][8]
#define C1B_OFF    73728     // bf16 [32][128]
#define EMBB_OFF   81920     // bf16 [32][256]
#define OUTB_OFF   98304     // bf16 [64][128]
#define C2PB_OFF   114688    // bf16 [256][288] tap-major (zeros for oc>=200)
#define WEFF_OFF   262144    // bf16 [32][256] = conv1 @ W_red
#define CAT2_OFF   524288    // bf16 [8*16384][128] pixel-major
#define MIX_OFF    34078720  // bf16 [8*16384][32]  pixel-major

__device__ __forceinline__ float bf2f(u16 x){ u32 u=((u32)x)<<16; float f; __builtin_memcpy(&f,&u,4); return f; }
__device__ __forceinline__ u16 f2bf(float f){ u32 u; __builtin_memcpy(&u,&f,4); return (u16)((u + 0x7fffu + ((u>>16)&1u))>>16); }
__device__ __forceinline__ u32 pk2(float a, float b){ return (u32)f2bf(a) | ((u32)f2bf(b)<<16); }
__device__ __forceinline__ float lrelu(float x){ return x>0.f ? x : 0.01f*x; }

template<int M> __device__ __forceinline__ u16 ldb(const void* p, size_t i){
    if (M==1) return ((const u16*)p)[i];
    return f2bf(((const float*)p)[i]);
}
template<int M> __device__ __forceinline__ float ldf(const void* p, size_t i){
    if (M==1) return bf2f(((const u16*)p)[i]);
    return ((const float*)p)[i];
}
// bijective swizzle over pixel-octet AND pixel-within-octet
__device__ __forceinline__ int swz(int p){ return ((p>>1) ^ (p>>3)) & 7; }

// async global->LDS, 16B per lane: LDS dest = uniform base + lane*16; global src per-lane
__device__ __forceinline__ void gl16(const void* g, void* l){
    __builtin_amdgcn_global_load_lds(
        (const __attribute__((address_space(1))) u32*)g,
        (__attribute__((address_space(3))) u32*)l, 16, 0, 0);
}

// quarter-unit fp32 transpose: 2 rows (r, r+1; channels 2jq,2jq+1 of the slot) x 8 px -> 8x u32
// raw rows: 64 floats, staged with px-quad XOR v; read undoes it.
__device__ __forceinline__ void transq_f32(
    const float* rawb, int ibuf, int rlo, int v, int po, u16* dst, int atChunk, int jq)
{
    const float* base = rawb + ibuf*256 + rlo*64;
    float fa[4], fb[4], ga[4], gb[4];
    int qa = ((2*po)^v)*4, qb = ((2*po+1)^v)*4;
    __builtin_memcpy(fa, base + qa, 16);        // row r,   px 8po..8po+3
    __builtin_memcpy(fb, base + qb, 16);        // row r,   px 8po+4..8po+7
    __builtin_memcpy(ga, base + 64 + qa, 16);   // row r+1
    __builtin_memcpy(gb, base + 64 + qb, 16);
#pragma unroll
    for (int p=0;p<8;p++){
        float x0 = (p<4) ? fa[p] : fb[p-4];
        float x1 = (p<4) ? ga[p] : gb[p-4];
        int pg = 8*po + p;
        *(u32*)(dst + pg*264 + ((atChunk ^ swz(pg))<<3) + jq*2) = pk2(x0, x1);
    }
}

// ---------------- dtype detector ----------------
__global__ void detect_kernel(const void* __restrict__ emb, u32* __restrict__ flag){
    int tid = threadIdx.x;
    const u16* p = (const u16*)emb;
    int e = (p[tid*2] >> 7) & 0xFF;
    u64 m = __ballot(e >= 100 && e <= 140);
    if (tid == 0) *flag = (__popcll(m) >= 32) ? 1u : 0u;
}

// ---------------- prep ----------------
template<int M>
__device__ __forceinline__ void prep_body(
    const void* rw, const void* rb, const void* c1w, const void* c1b,
    const void* c2w, const void* c2b, const void* ew, const void* eb,
    const void* ow, const void* ob, const void* gam, const void* bet,
    const void* mn, const void* vr, char* ws)
{
    float* wf = (float*)ws;
    int i = blockIdx.x*256 + threadIdx.x;
    if (i < 32768) {
        int o = i>>8, ic = i&255;
        int s = ic>>4, qq = (ic>>3)&1, e = ic&7;
        int dst = (((o>>5)*16 + s)*64 + qq*32 + (o&31))*8 + e;
        ((u16*)(ws+RWB_OFF))[dst] = ldb<M>(rw, i);
    }
    else if (i < 36864)  ((u16*)(ws+C1B_OFF))[i-32768] = ldb<M>(c1w, i-32768);
    else if (i < 45056)  ((u16*)(ws+EMBB_OFF))[i-36864] = ldb<M>(ew, i-36864);
    else if (i < 53248)  ((u16*)(ws+OUTB_OFF))[i-45056] = ldb<M>(ow, i-45056);
    else if (i < 126976) {
        int j = i-53248; int o = j/288, k = j - o*288;
        int tap = k>>5, ic = k&31;
        u16 v = 0;
        if (o < 200) v = ldb<M>(c2w, (size_t)o*288 + ic*9 + tap);
        ((u16*)(ws+C2PB_OFF))[j] = v;
    }
    else if (i < 127584) {
        int j = i-126976;
        if (j < 128) wf[RED_B+j] = ldf<M>(rb, j);
        else if (j < 160) {
            int o = j-128;
            float s = ldf<M>(c1b,o) + ldf<M>(eb,o);
#pragma unroll 8
            for (int ic=0; ic<128; ic++)
                s += ldf<M>(c1w, (size_t)o*128+ic) * ldf<M>(rb, ic);
            wf[C1E_B+o] = s;
        }
        else if (j < 416) { int o = j-160; wf[C2_B+o] = (o<200) ? ldf<M>(c2b,o) : 0.f; }
        else if (j < 480) wf[OUT_B+j-416] = ldf<M>(ob, j-416);
        else if (j < 544) { int c=j-480; wf[BN_SC+c] = ldf<M>(gam,c) * rsqrtf(ldf<M>(vr,c)+1e-5f); }
        else { int c=j-544; wf[BN_SH+c] = ldf<M>(bet,c) - ldf<M>(mn,c)*ldf<M>(gam,c)*rsqrtf(ldf<M>(vr,c)+1e-5f); }
    }
    else if (i < 135776) {
        int j = i - 127584; int oc = j>>8, k2 = j&255;
        float s = 0.f;
#pragma unroll 8
        for (int ic=0; ic<128; ic++)
            s += ldf<M>(c1w, (size_t)oc*128+ic) * ldf<M>(rw, (size_t)ic*256+k2);
        ((u16*)(ws+WEFF_OFF))[oc*256+k2] = f2bf(s);
    }
}

__global__ __launch_bounds__(256) void k_prep(
    const void* rw, const void* rb, const void* c1w, const void* c1b,
    const void* c2w, const void* c2b, const void* ew, const void* eb,
    const void* ow, const void* ob, const void* gam, const void* bet,
    const void* mn, const void* vr, char* ws, const u32* __restrict__ flag)
{
    if (*flag) prep_body<1>(rw,rb,c1w,c1b,c2w,c2b,ew,eb,ow,ob,gam,bet,mn,vr,ws);
    else       prep_body<0>(rw,rb,c1w,c1b,c2w,c2b,ew,eb,ow,ob,gam,bet,mn,vr,ws);
}

// ---------------- fp32 (LIVE) fused reduce+mix: async staging, 40KB raw, 2 blk/CU ----------------
// grid 2048, 512 thr. LDS 74.75 KB = raw 40 KB (time-muxed) + At 33.8 KB.
//  S_A lo[0..31] -> raw    | bar | T_A -> At chunks 4..19  | bar
//  S_B lo[32..55]+hi -> raw| bar | T_B -> At 20..31 + 0..3 | bar
//  S_C emb[0..31] -> raw ; P1a (reduce 16 + mix 4 MFMA) -> cat2 | bar
//  T_CA -> At 0..15 | bar ; S_D emb[32..63] ; P1b_lo (ks<2) | bar
//  T_CB -> At 16..31 | bar ; P1b_hi (ks>=2) ; P4 exch via raw -> mixt
__global__ __launch_bounds__(512) void k_rmf(
    const void* __restrict__ hi, const void* __restrict__ lo, const void* __restrict__ emb,
    const u16* __restrict__ rwB, const u16* __restrict__ weffB, const u16* __restrict__ embB,
    const float* __restrict__ wf, u16* __restrict__ cat2, u16* __restrict__ mixt,
    const u32* __restrict__ flag)
{
    if (*flag != 0u) return;
    __shared__ char ldsb[40960 + 64*264*2];   // 74752 B total
    float* rawf = (float*)ldsb;               // 40960 B staging, reused 4x, then exch
    u16* At = (u16*)(ldsb + 40960);           // 33792 B

    const int tid = threadIdx.x, wvi = tid>>6, lane = tid&63;
    const int col = lane&31, q = lane>>5;
    const int gpx = blockIdx.x*64;
    const int b = gpx>>14, p0 = gpx&16383;
    const int h = p0>>7, w0 = p0&127;
    const int pt = wvi>>2, ks = wvi&3;

    // ---- S_A: lo chunks 0..31 ----
    for (int i=wvi; i<32; i+=8){
        int r = 4*i + (lane>>4);
        int qd = (lane&15) ^ (i&15);
        gl16((const float*)lo + ((size_t)(b*224 + r))*HW + p0 + qd*4, (char*)rawf + i*1024);
    }
    __syncthreads();   // bar1

    // ---- T_A: lo channels 0..127 -> At chunks 4..19 (512 units) ----
    {
        const int c = tid>>5, po = (tid>>2)&7, jq = tid&3;
        int r = 8*c + 2*jq;
        transq_f32(rawf, r>>2, r&3, (r>>2)&15, po, At, 4+c, jq);
    }
    __syncthreads();   // bar2

    // ---- S_B: lo chunks 32..55 -> buf 0..23 ; hi chunks 0..15 -> buf 24..39 ----
    for (int idx=wvi; idx<24; idx+=8){
        int ig = 32 + idx;
        int r = 4*ig + (lane>>4);
        int qd = (lane&15) ^ (ig&15);
        gl16((const float*)lo + ((size_t)(b*224 + r))*HW + p0 + qd*4, (char*)rawf + idx*1024);
    }
    for (int idx=wvi; idx<16; idx+=8){
        int hc = 8*idx + (lane>>3);
        int qd = (lane&7) ^ (idx&7);
        gl16((const float*)hi + ((size_t)(b*128 + hc))*4096 + (size_t)(h>>1)*64 + (w0>>1) + qd*4,
             (char*)rawf + (24+idx)*1024);
    }
    __syncthreads();   // bar3

    // ---- T_B: lo channels 128..223 -> At 20..31 (384 units); hi -> At 0..3 (128 units) ----
    if (tid < 384){
        const int c = tid>>5, po = (tid>>2)&7, jq = tid&3;
        int rg = 128 + 8*c + 2*jq;
        int ig = rg>>2;
        transq_f32(rawf, ig-32, rg&3, ig&15, po, At, 20+c, jq);
    } else {
        const int u = tid-384, co = u>>5, po = (u>>2)&7, jj = u&3;
        const int h2 = (h&1)*2;
        const float* hbase = rawf + 6144;   // byte 24576
        float fe0[4], fo0[4], fe1[4], fo1[4];
        {
            int hcA = (8*co + 2*jj)*4 + h2;
            int hcB = (8*co + 2*jj + 1)*4 + h2;
            int sA = po ^ ((hcA>>3)&7);
            int sB = po ^ ((hcB>>3)&7);
            __builtin_memcpy(fe0, hbase + hcA*32 + sA*4, 16);
            __builtin_memcpy(fo0, hbase + (hcA+1)*32 + sA*4, 16);
            __builtin_memcpy(fe1, hbase + hcB*32 + sB*4, 16);
            __builtin_memcpy(fo1, hbase + (hcB+1)*32 + sB*4, 16);
        }
#pragma unroll
        for (int p=0;p<8;p++){
            float x0 = (p&1) ? fo0[p>>1] : fe0[p>>1];
            float x1 = (p&1) ? fo1[p>>1] : fe1[p>>1];
            int pg = 8*po + p;
            *(u32*)(At + pg*264 + ((co ^ swz(pg))<<3) + jj*2) = pk2(x0, x1);
        }
    }
    __syncthreads();   // bar4: At(concat) complete

    // ---- S_C: emb chunks 0..31 (latency hides under P1a) ----
    for (int i=wvi; i<32; i+=8){
        int r = 4*i + (lane>>4);
        int qd = (lane&15) ^ (i&15);
        gl16((const float*)emb + ((size_t)(b*256 + r))*HW + p0 + qd*4, (char*)rawf + i*1024);
    }

    // ---- P1a: reduce 16 MFMA + mix-partial 4 MFMA (same A-frags) ----
    const int pp = pt*32 + col, sw = swz(pp);
    const u16* arow = At + pp*264;

    f32x16 racc, macc;
#pragma unroll
    for (int r=0;r<16;r++){ racc[r]=0.f; macc[r]=0.f; }

    short8 Wf[4];
#pragma unroll
    for (int t4=0;t4<4;t4++)
        __builtin_memcpy(&Wf[t4], weffB + (size_t)col*256 + (4*ks+t4)*16 + q*8, 16);

#pragma unroll
    for (int bt=0; bt<4; bt++){
        short8 Bb[4];
#pragma unroll
        for (int si=0;si<4;si++)
            __builtin_memcpy(&Bb[si], rwB + (((size_t)(ks*16 + bt*4 + si))*64 + lane)*8, 16);
#pragma unroll
        for (int si=0;si<4;si++){
            int s = bt*4 + si;
            short8 a; __builtin_memcpy(&a, arow + (((2*s+q)^sw)<<3), 16);
            racc = __builtin_amdgcn_mfma_f32_32x32x16_bf16(a, Bb[si], racc, 0,0,0);
            int d = s - 4*ks;
            if (d>=0 && d<4)
                macc = __builtin_amdgcn_mfma_f32_32x32x16_bf16(a, Wf[d], macc, 0,0,0);
        }
    }
    {
        int oc = ks*32 + col;
        float bias = wf[RED_B + oc];
#pragma unroll
        for (int r=0;r<16;r++){
            int row = (r&3) + 8*(r>>2) + 4*q;
            cat2[((size_t)(gpx + pt*32 + row))*128 + oc] = f2bf(racc[r] + bias);
        }
    }
    __syncthreads();   // bar5: emb[0..31] landed; At(concat) reads done

    // ---- T_CA: emb channels 0..127 -> At chunks 0..15 ----
    {
        const int c = tid>>5, po = (tid>>2)&7, jq = tid&3;
        int r = 8*c + 2*jq;
        transq_f32(rawf, r>>2, r&3, (r>>2)&15, po, At, c, jq);
    }
    __syncthreads();   // bar6: At 0..15 ready; rawf[emb lo] reads done

    // ---- S_D: emb chunks 32..63 ----
    for (int idx=wvi; idx<32; idx+=8){
        int ig = 32 + idx;
        int r = 4*ig + (lane>>4);
        int qd = (lane&15) ^ (ig&15);
        gl16((const float*)emb + ((size_t)(b*256 + r))*HW + p0 + qd*4, (char*)rawf + idx*1024);
    }

    // ---- P1b_lo: waves ks<2, k-steps 4ks..4ks+3 (emb ch 0..127 -> At 0..15) ----
    if (ks < 2){
        short8 Be[4];
#pragma unroll
        for (int t4=0;t4<4;t4++)
            __builtin_memcpy(&Be[t4], embB + (size_t)col*256 + (4*ks+t4)*16 + q*8, 16);
#pragma unroll
        for (int t4=0;t4<4;t4++){
            int t = 4*ks + t4;
            short8 a; __builtin_memcpy(&a, arow + (((2*t+q)^sw)<<3), 16);
            macc = __builtin_amdgcn_mfma_f32_32x32x16_bf16(a, Be[t4], macc, 0,0,0);
        }
    }
    __syncthreads();   // bar7: emb[32..63] landed; At 0..15 reads done (ks<2 done)

    // ---- T_CB: emb channels 128..255 -> At chunks 16..31 ----
    {
        const int c = tid>>5, po = (tid>>2)&7, jq = tid&3;
        int rg = 128 + 8*c + 2*jq;
        int ig = rg>>2;
        transq_f32(rawf, ig-32, rg&3, ig&15, po, At, 16+c, jq);
    }
    __syncthreads();   // bar8: At 16..31 ready; rawf free

    // ---- P1b_hi: waves ks>=2, k-steps 8..15 ----
    if (ks >= 2){
        short8 Be[4];
#pragma unroll
        for (int t4=0;t4<4;t4++)
            __builtin_memcpy(&Be[t4], embB + (size_t)col*256 + (4*ks+t4)*16 + q*8, 16);
#pragma unroll
        for (int t4=0;t4<4;t4++){
            int t = 4*ks + t4;
            short8 a; __builtin_memcpy(&a, arow + (((2*t+q)^sw)<<3), 16);
            macc = __builtin_amdgcn_mfma_f32_32x32x16_bf16(a, Be[t4], macc, 0,0,0);
        }
    }

    // ---- P4: combine 4 K-partials via rawf-as-exch ----
    float* exch = rawf;
    if (ks != 0){
#pragma unroll
        for (int r=0;r<16;r++){
            int row = (r&3) + 8*(r>>2) + 4*q;
            exch[pt*3072 + (ks-1)*1024 + row*32 + col] = macc[r];
        }
    }
    __syncthreads();   // bar9
    if (ks == 0){
        float bias = wf[C1E_B + col];
#pragma unroll
        for (int r=0;r<16;r++){
            int row = (r&3) + 8*(r>>2) + 4*q;
            int base = pt*3072 + row*32 + col;
            float v = macc[r] + exch[base] + exch[base+1024] + exch[base+2048] + bias;
            mixt[((size_t)(gpx + pt*32 + row))*32 + col] = f2bf(lrelu(v));
        }
    }
}

// ---------------- bf16 (dead-path) fused reduce+mix: round-9 async version ----------------
__global__ __launch_bounds__(512) void k_rm(
    const void* __restrict__ hi, const void* __restrict__ lo, const void* __restrict__ emb,
    const u16* __restrict__ rwB, const u16* __restrict__ weffB, const u16* __restrict__ embB,
    const float* __restrict__ wf, u16* __restrict__ cat2, u16* __restrict__ mixt,
    const u32* __restrict__ flag)
{
    if (*flag != 1u) return;
    __shared__ u16 At1[64*264];
    __shared__ u16 At2[64*264];
    __shared__ u16 raw[34816];

    const int tid = threadIdx.x, wvi = tid>>6, lane = tid&63;
    const int col = lane&31, q = lane>>5;
    const int gpx = blockIdx.x*64;
    const int b = gpx>>14, p0 = gpx&16383;
    const int h = p0>>7, w0 = p0&127;

    {
        for (int i=wvi; i<28; i+=8){
            int chunk = i*64 + lane;
            int ch = chunk>>3, p8 = chunk&7;
            gl16((const u16*)lo + ((size_t)(b*224+ch))*HW + p0 + p8*8,
                 (char*)raw + i*1024);
        }
        {
            int i = wvi;
            int chunk = i*64 + lane;
            int hc = chunk>>2, c4 = chunk&3;
            gl16((const u16*)hi + ((size_t)(b*128+hc))*4096 + (size_t)(h>>1)*64 + (w0>>1) + c4*8,
                 (char*)raw + 28672 + i*1024);
        }
        for (int i=wvi; i<32; i+=8){
            int chunk = i*64 + lane;
            int ch = chunk>>3, p8 = chunk&7;
            gl16((const u16*)emb + ((size_t)(b*256+ch))*HW + p0 + p8*8,
                 (char*)raw + 36864 + i*1024);
        }
    }
    __syncthreads();

    {
        const int sthr = tid & 255;
        const int co = sthr>>3, po = sthr&7;
        u32 W[8][4];
        if (tid >= 256) {
            u32 R[8][4];
#pragma unroll
            for (int j=0;j<8;j++)
                __builtin_memcpy(&R[j][0], raw + 18432 + (8*co+j)*64 + po*8, 16);
#pragma unroll
            for (int p=0;p<8;p++){
                const int u = p>>1, hf = p&1;
#pragma unroll
                for (int m=0;m<4;m++){
                    u32 A0 = R[2*m][u], A1 = R[2*m+1][u];
                    W[p][m] = hf ? ((A0>>16) | (A1 & 0xffff0000u))
                                 : ((A0 & 0xffffu) | (A1<<16));
                }
            }
#pragma unroll
            for (int p=0;p<8;p++){
                int pg = 8*po + p;
                __builtin_memcpy(At2 + pg*264 + ((co ^ swz(pg))<<3), &W[p][0], 16);
            }
        } else if (co >= 4) {
            u32 R[8][4];
#pragma unroll
            for (int j=0;j<8;j++)
                __builtin_memcpy(&R[j][0], raw + (8*(co-4)+j)*64 + po*8, 16);
#pragma unroll
            for (int p=0;p<8;p++){
                const int u = p>>1, hf = p&1;
#pragma unroll
                for (int m=0;m<4;m++){
                    u32 A0 = R[2*m][u], A1 = R[2*m+1][u];
                    W[p][m] = hf ? ((A0>>16) | (A1 & 0xffff0000u))
                                 : ((A0 & 0xffffu) | (A1<<16));
                }
            }
#pragma unroll
            for (int p=0;p<8;p++){
                int pg = 8*po + p;
                __builtin_memcpy(At1 + pg*264 + ((co ^ swz(pg))<<3), &W[p][0], 16);
            }
        } else {
            const int h2 = (h&1)*2;
            u32 E[8][2], O[8][2];
#pragma unroll
            for (int j=0;j<8;j++){
                int hc = (8*co+j)*4 + h2;
                __builtin_memcpy(&E[j][0], raw + 14336 + hc*32 + po*4, 8);
                __builtin_memcpy(&O[j][0], raw + 14336 + (hc+1)*32 + po*4, 8);
            }
#pragma unroll
            for (int p=0;p<8;p++){
                const int k = p>>1, u = k>>1, hf = k&1;
#pragma unroll
                for (int m=0;m<4;m++){
                    u32 A0, A1;
                    if (p&1){ A0 = O[2*m][u]; A1 = O[2*m+1][u]; }
                    else    { A0 = E[2*m][u]; A1 = E[2*m+1][u]; }
                    W[p][m] = hf ? ((A0>>16) | (A1 & 0xffff0000u))
                                 : ((A0 & 0xffffu) | (A1<<16));
                }
            }
#pragma unroll
            for (int p=0;p<8;p++){
                int pg = 8*po + p;
                __builtin_memcpy(At1 + pg*264 + ((co ^ swz(pg))<<3), &W[p][0], 16);
            }
        }
    }
    __syncthreads();

    const int pt = wvi>>2, ks = wvi&3;
    const int pp = pt*32 + col, sw = swz(pp);
    const u16* arow1 = At1 + pp*264;
    const u16* arow2 = At2 + pp*264;

    f32x16 racc, macc;
#pragma unroll
    for (int r=0;r<16;r++){ racc[r]=0.f; macc[r]=0.f; }

    short8 Wf[4], Be2[4];
#pragma unroll
    for (int t4=0;t4<4;t4++)
        __builtin_memcpy(&Wf[t4], weffB + (size_t)col*256 + (4*ks+t4)*16 + q*8, 16);
#pragma unroll
    for (int t4=0;t4<4;t4++)
        __builtin_memcpy(&Be2[t4], embB + (size_t)col*256 + (4*ks+t4)*16 + q*8, 16);

#pragma unroll
    for (int bt=0; bt<4; bt++){
        short8 Bb[4];
#pragma unroll
        for (int si=0;si<4;si++)
            __builtin_memcpy(&Bb[si], rwB + (((size_t)(ks*16 + bt*4 + si))*64 + lane)*8, 16);
#pragma unroll
        for (int si=0;si<4;si++){
            int s = bt*4 + si;
            short8 a; __builtin_memcpy(&a, arow1 + (((2*s+q)^sw)<<3), 16);
            racc = __builtin_amdgcn_mfma_f32_32x32x16_bf16(a, Bb[si], racc, 0,0,0);
            int d = s - 4*ks;
            if (d>=0 && d<4)
                macc = __builtin_amdgcn_mfma_f32_32x32x16_bf16(a, Wf[d], macc, 0,0,0);
        }
    }
#pragma unroll
    for (int t4=0;t4<4;t4++){
        int t = 4*ks + t4;
        short8 a; __builtin_memcpy(&a, arow2 + (((2*t+q)^sw)<<3), 16);
        macc = __builtin_amdgcn_mfma_f32_32x32x16_bf16(a, Be2[t4], macc, 0,0,0);
    }
    {
        int oc = ks*32 + col;
        float bias = wf[RED_B + oc];
#pragma unroll
        for (int r=0;r<16;r++){
            int row = (r&3) + 8*(r>>2) + 4*q;
            cat2[((size_t)(gpx + pt*32 + row))*128 + oc] = f2bf(racc[r] + bias);
        }
    }

    float* exch = (float*)raw;
    if (ks != 0){
#pragma unroll
        for (int r=0;r<16;r++){
            int row = (r&3) + 8*(r>>2) + 4*q;
            exch[pt*3072 + (ks-1)*1024 + row*32 + col] = macc[r];
        }
    }
    __syncthreads();
    if (ks == 0){
        float bias = wf[C1E_B + col];
#pragma unroll
        for (int r=0;r<16;r++){
            int row = (r&3) + 8*(r>>2) + 4*q;
            int base = pt*3072 + row*32 + col;
            float v = macc[r] + exch[base] + exch[base+1024] + exch[base+2048] + bias;
            mixt[((size_t)(gpx + pt*32 + row))*32 + col] = f2bf(lrelu(v));
        }
    }
}

// ---------------- fused conv2 + involution + out conv + BN + lrelu ----------------
template<int M>
__device__ __forceinline__ void inv_body(
    const u16* __restrict__ cat2, const u16* __restrict__ mixt,
    const u16* __restrict__ c2B, const u16* __restrict__ outB,
    const float* __restrict__ wf, void* __restrict__ out,
    u16* halo_m, u16* wgt_l, u16* halo_c, u16* og)
{
    const int tid = threadIdx.x, wvi = tid>>6, lane = tid&63;
    const int col = lane&31, q = lane>>5;
    const int b = blockIdx.y, ty = blockIdx.x>>3, tx = blockIdx.x&7;
    const int py = tid>>4, px = tid&15;

    f32x16 acc[2][2];
#pragma unroll
    for (int i=0;i<2;i++)
#pragma unroll
    for (int j=0;j<2;j++)
#pragma unroll
    for (int r=0;r<16;r++) acc[i][j][r] = 0.f;

#pragma unroll
    for (int i=0;i<6;i++){
        int idx = tid + i*256;
        if (idx < 1296){
            int point = idx>>2, cq = idx&3;
            int y = ty*16 + point/18 - 1, x = tx*16 + point%18 - 1;
            short8 v;
            if (y>=0 && y<128 && x>=0 && x<128)
                __builtin_memcpy(&v, mixt + ((size_t)(b*HW + y*128 + x))*32 + cq*8, 16);
            else { short z=0; v = (short8){z,z,z,z,z,z,z,z}; }
            *(short8*)(halo_m + point*40 + cq*8) = v;
        }
    }
    __syncthreads();

#pragma unroll 1
    for (int g=0; g<8; g++){
        __syncthreads();

        const int o = g*25 + col;
        short8 Bf[18];
#pragma unroll
        for (int s=0;s<18;s++)
            __builtin_memcpy(&Bf[s], c2B + (size_t)o*288 + s*16 + q*8, 16);

#pragma unroll
        for (int i=0;i<4;i++){
            int idx = tid + i*256;
            if (idx < 800){
                int point = idx>>1, cq = idx&1;
                int y = ty*16 + point/20 - 2, x = tx*16 + point%20 - 2;
                short8 v;
                if (y>=0 && y<128 && x>=0 && x<128)
                    __builtin_memcpy(&v, cat2 + ((size_t)(b*HW + y*128 + x))*128 + g*16 + cq*8, 16);
                else { short z=0; v = (short8){z,z,z,z,z,z,z,z}; }
                *(short8*)(halo_c + point*16 + cq*8) = v;
            }
        }

        f32x16 c0, c1;
#pragma unroll
        for (int r=0;r<16;r++){ c0[r]=0.f; c1[r]=0.f; }
        const int p0 = wvi*64 + col, p1 = p0 + 32;
        const int pya = p0>>4, pxa = p0&15, pyb = p1>>4, pxb = p1&15;
#pragma unroll
        for (int s=0;s<18;s++){
            int tap = s>>1, ih = s&1;
            int dy = tap/3, dx = tap%3;
            short8 a0, a1;
            __builtin_memcpy(&a0, halo_m + ((pya+dy)*18 + pxa+dx)*40 + ih*16 + q*8, 16);
            __builtin_memcpy(&a1, halo_m + ((pyb+dy)*18 + pxb+dx)*40 + ih*16 + q*8, 16);
            c0 = __builtin_amdgcn_mfma_f32_32x32x16_bf16(a0, Bf[s], c0, 0,0,0);
            c1 = __builtin_amdgcn_mfma_f32_32x32x16_bf16(a1, Bf[s], c1, 0,0,0);
        }
        {
            float bias = wf[C2_B + o];
#pragma unroll
            for (int rt2=0; rt2<2; rt2++){
                int mb = wvi*64 + rt2*32;
#pragma unroll
                for (int r=0;r<16;r+=2){
                    int row0 = (r&3) + 8*(r>>2) + 4*q;
                    float v0 = (rt2 ? c1[r]   : c0[r])   + bias;
                    float v1 = (rt2 ? c1[r+1] : c0[r+1]) + bias;
                    u32 pkv = (u32)f2bf(v0) | ((u32)f2bf(v1)<<16);
                    *(u32*)(wgt_l + (size_t)col*264 + mb + row0) = pkv;
                }
            }
        }
        __syncthreads();

        float wvv[25];
#pragma unroll
        for (int t=0;t<25;t++) wvv[t] = bf2f(wgt_l[t*264 + tid]);

        float a16[16];
#pragma unroll
        for (int cc=0;cc<16;cc++) a16[cc]=0.f;
#pragma unroll
        for (int t=0;t<25;t++){
            int dy = t/5, dx = t%5;
            u32 vv[8];
            __builtin_memcpy(vv, halo_c + ((py+dy)*20 + px+dx)*16, 32);
            float wt = wvv[t];
#pragma unroll
            for (int r=0;r<8;r++){
                u32 u = vv[r];
                u32 ulo = u<<16, uhi = u & 0xffff0000u;
                float x0, x1;
                __builtin_memcpy(&x0,&ulo,4); __builtin_memcpy(&x1,&uhi,4);
                a16[2*r]   += wt*x0;
                a16[2*r+1] += wt*x1;
            }
        }
        u32 pk[8];
#pragma unroll
        for (int r=0;r<8;r++) pk[r] = (u32)f2bf(a16[2*r]) | ((u32)f2bf(a16[2*r+1])<<16);
        __builtin_memcpy(og + tid*16, pk, 32);
        __syncthreads();

        short8 bo0, bo1;
        __builtin_memcpy(&bo0, outB + (size_t)(col)*128      + g*16 + q*8, 16);
        __builtin_memcpy(&bo1, outB + (size_t)(32+col)*128   + g*16 + q*8, 16);
#pragma unroll
        for (int rt2=0; rt2<2; rt2++){
            int prow = (wvi*2 + rt2)*32 + col;
            short8 a; __builtin_memcpy(&a, og + prow*16 + q*8, 16);
            acc[rt2][0] = __builtin_amdgcn_mfma_f32_32x32x16_bf16(a, bo0, acc[rt2][0], 0,0,0);
            acc[rt2][1] = __builtin_amdgcn_mfma_f32_32x32x16_bf16(a, bo1, acc[rt2][1], 0,0,0);
        }
    }
#pragma unroll
    for (int rt2=0; rt2<2; rt2++)
#pragma unroll
    for (int nt=0; nt<2; nt++){
        int oc = nt*32 + col;
        float bias = wf[OUT_B+oc], sc = wf[BN_SC+oc], sh = wf[BN_SH+oc];
#pragma unroll
        for (int r=0;r<16;r++){
            int row = (r&3) + 8*(r>>2) + 4*q;
            int p = (wvi*2 + rt2)*32 + row;
            int yy = ty*16 + (p>>4), xx = tx*16 + (p&15);
            float v = lrelu((acc[rt2][nt][r] + bias)*sc + sh);
            size_t oidx = ((size_t)(b*64 + oc))*HW + yy*128 + xx;
            if (M==1) ((u16*)out)[oidx] = f2bf(v);
            else ((float*)out)[oidx] = v;
        }
    }
}

__global__ __launch_bounds__(256,2) void k_inv(
    const u16* __restrict__ cat2, const u16* __restrict__ mixt,
    const u16* __restrict__ c2B, const u16* __restrict__ outB,
    const float* __restrict__ wf, void* __restrict__ out, const u32* __restrict__ flag)
{
    __shared__ u16 halo_m[324*40];
    __shared__ u16 wgt_l[32*264];
    __shared__ u16 halo_c[400*16];
    __shared__ u16 og[256*16];
    if (*flag) inv_body<1>(cat2, mixt, c2B, outB, wf, out, halo_m, wgt_l, halo_c, og);
    else       inv_body<0>(cat2, mixt, c2B, outB, wf, out, halo_m, wgt_l, halo_c, og);
}

extern "C" void kernel_launch(void* const* d_in, const int* in_sizes, int n_in,
                              void* d_out, int out_size, void* d_ws, size_t ws_size,
                              hipStream_t stream) {
    const void* hi  = d_in[0];
    const void* lo  = d_in[1];
    const void* emb = d_in[2];
    char* ws = (char*)d_ws;
    float* wf = (float*)ws;
    u32* flag = (u32*)(ws + FLAG_OFF);
    u16* cat2 = (u16*)(ws + CAT2_OFF);
    u16* mixt = (u16*)(ws + MIX_OFF);

    detect_kernel<<<1, 64, 0, stream>>>(emb, flag);

    k_prep<<<531,256,0,stream>>>(d_in[3],d_in[4],d_in[5],d_in[6],d_in[7],d_in[8],
        d_in[9],d_in[10],d_in[11],d_in[12],d_in[13],d_in[14],d_in[15],d_in[16], ws, flag);

    k_rmf<<<2048,512,0,stream>>>(hi, lo, emb, (const u16*)(ws+RWB_OFF),
                                 (const u16*)(ws+WEFF_OFF), (const u16*)(ws+EMBB_OFF),
                                 wf, cat2, mixt, flag);
    k_rm<<<2048,512,0,stream>>>(hi, lo, emb, (const u16*)(ws+RWB_OFF),
                                (const u16*)(ws+WEFF_OFF), (const u16*)(ws+EMBB_OFF),
                                wf, cat2, mixt, flag);

    k_inv<<<dim3(64,8),256,0,stream>>>(cat2, mixt, (const u16*)(ws+C2PB_OFF),
                                       (const u16*)(ws+OUTB_OFF), wf, d_out, flag);
}